// Round 6
// baseline (826.691 us; speedup 1.0000x reference)
//
#include <hip/hip_runtime.h>
#include <hip/hip_bf16.h>
#include <math.h>

// ---------------------------------------------------------------------------
// CapsuleNetwork forward.
// FAST PATH (ws_size >= 499 MB): pcaps conv as split-bf16 MFMA GEMM.
//   conv1   : img -> x[128,256,20,20]
//   im2col  : x -> A_f, bf16 hi/lo fragments in MFMA lane order
//             A[m=b*36+pos][k=ic*81+ky*9+kx], record per (q,mt,ks):
//             [hi mf0|hi mf1|lo mf0|lo mf1] x 64 lanes x 16B
//   wsplit  : pcaps_w -> W_f, bf16 hi/lo fragments [q][ks][hi nf0..7|lo nf0..7]
//   gemm    : C = A*W via 3-pass split (hihi+hilo+lohi), 32x32x16 bf16 MFMA,
//             no LDS / no barriers; split-K=8 -> part[8][...]
//   squash  : part(+bias) -> u ; routing: u -> out
// FALLBACK: R5 fp32 direct-conv path (wtrans + pcaps).
// ---------------------------------------------------------------------------

typedef __attribute__((ext_vector_type(8)))  short  short8;
typedef __attribute__((ext_vector_type(8)))  ushort ushort8v;
typedef __attribute__((ext_vector_type(16))) float  f32x16;
#define MFMA32(a, b, c) __builtin_amdgcn_mfma_f32_32x32x16_bf16(a, b, c, 0, 0, 0)

__device__ __forceinline__ void split_bf16(float v, ushort& h, ushort& l) {
    __hip_bfloat16 hb = __float2bfloat16(v);
    float hf = __bfloat162float(hb);
    __hip_bfloat16 lb = __float2bfloat16(v - hf);
    h = *reinterpret_cast<ushort*>(&hb);
    l = *reinterpret_cast<ushort*>(&lb);
}

// ------------------------------- conv1 -------------------------------------
__global__ __launch_bounds__(256) void conv1_kernel(
    const float* __restrict__ img, const float* __restrict__ w,
    const float* __restrict__ bias, float* __restrict__ x)
{
    const int ct = blockIdx.x;
    const int b  = blockIdx.y;
    const int t  = threadIdx.x;
    __shared__ float img_s[784];
    __shared__ float w_s[64 * 81];
    for (int idx = t; idx < 784; idx += 256) img_s[idx] = img[b * 784 + idx];
    for (int idx = t; idx < 64 * 81; idx += 256) w_s[idx] = w[ct * 64 * 81 + idx];
    __syncthreads();
    for (int task = t; task < 1280; task += 256) {
        const int cl = task / 20;
        const int oy = task - cl * 20;
        float acc[20];
        const float bv = bias[ct * 64 + cl];
#pragma unroll
        for (int j = 0; j < 20; ++j) acc[j] = bv;
#pragma unroll
        for (int ky = 0; ky < 9; ++ky) {
            float rowv[28];
            const float* r = &img_s[(oy + ky) * 28];
#pragma unroll
            for (int j = 0; j < 28; ++j) rowv[j] = r[j];
#pragma unroll
            for (int kx = 0; kx < 9; ++kx) {
                const float wv = w_s[cl * 81 + ky * 9 + kx];
#pragma unroll
                for (int j = 0; j < 20; ++j) acc[j] += wv * rowv[j + kx];
            }
        }
        float* xp = x + (((size_t)b * 256 + ct * 64 + cl) * 400) + oy * 20;
#pragma unroll
        for (int j = 0; j < 20; ++j) xp[j] = fmaxf(acc[j], 0.f);
    }
}

// ------------------------------ im2col (fast) ------------------------------
// thread -> one A fragment lane (8 k-values) for one (q,mt,ks,mf); writes hi+lo.
__global__ __launch_bounds__(256) void im2col_kernel(
    const float* __restrict__ x, ushort* __restrict__ Af)
{
    const int bx  = blockIdx.x;          // 8*72*81 = 46656
    const int t   = threadIdx.x;
    const int ks2 = bx % 81;
    const int mtq = bx / 81;
    const int mt  = mtq % 72;
    const int q   = mtq / 72;
    const int lane = t & 63;
    const int mf   = (t >> 6) & 1;
    const int ks   = ks2 * 2 + (t >> 7);
    const int m   = mt * 64 + mf * 32 + (lane & 31);
    const int b   = m / 36, pos = m - b * 36;
    const int oy  = pos / 6, ox = pos - oy * 6;
    const int k0  = q * 2592 + ks * 16 + (lane >> 5) * 8;
    int ic = k0 / 81;
    int r  = k0 - ic * 81;
    int ky = r / 9;
    int kx = r - ky * 9;
    const float* xp = x + (((size_t)b * 256 + ic) * 20 + (2 * oy + ky)) * 20 + 2 * ox + kx;
    ushort8v h8, l8;
#pragma unroll
    for (int j = 0; j < 8; ++j) {
        ushort hb, lb;
        split_bf16(*xp, hb, lb);
        h8[j] = hb; l8[j] = lb;
        if (kx == 8) {
            kx = 0;
            if (ky == 8) { ky = 0; ++ic; xp += 232; }
            else         { ++ky; xp += 12; }
        } else { ++kx; ++xp; }
    }
    ushort* rec = Af + ((size_t)(q * 72 + mt) * 162 + ks) * 2048;
    *(ushort8v*)(rec + mf * 512 + lane * 8)       = h8;
    *(ushort8v*)(rec + (2 + mf) * 512 + lane * 8) = l8;
}

// ------------------------------ wsplit (fast) ------------------------------
__global__ __launch_bounds__(256) void wsplit_kernel(
    const float* __restrict__ pw, ushort* __restrict__ Wf)
{
    const int bx = blockIdx.x;           // 8*162*2 = 2592
    const int t  = threadIdx.x;
    const int lane = t & 63;
    const int nf   = (bx & 1) * 4 + (t >> 6);
    const int ks   = (bx >> 1) % 162;
    const int q    = (bx >> 1) / 162;
    const int oc   = nf * 32 + (lane & 31);
    const int k0   = q * 2592 + ks * 16 + (lane >> 5) * 8;
    const float* wp = pw + (size_t)oc * 20736 + k0;
    ushort8v h8, l8;
#pragma unroll
    for (int j = 0; j < 8; ++j) {
        ushort hb, lb;
        split_bf16(wp[j], hb, lb);
        h8[j] = hb; l8[j] = lb;
    }
    ushort* rec = Wf + (size_t)(q * 162 + ks) * 8192;
    *(ushort8v*)(rec + nf * 512 + lane * 8)       = h8;
    *(ushort8v*)(rec + (8 + nf) * 512 + lane * 8) = l8;
}

// ------------------------------- gemm (fast) -------------------------------
// 576 blocks: q = bid&7 (XCD-resident W chunk), mt = bid>>3 (64-row M tile).
// 4 waves split N=256 into 64-col wave tiles; per wave 2x2 frags of 32x32.
__global__ __launch_bounds__(256) void gemm_kernel(
    const ushort* __restrict__ Af, const ushort* __restrict__ Wf,
    float* __restrict__ part)
{
    const int bid = blockIdx.x;
    const int q  = bid & 7, mt = bid >> 3;
    const int t  = threadIdx.x;
    const int w  = t >> 6, lane = t & 63;
    const ushort* Ab = Af + ((size_t)(q * 72 + mt) * 162) * 2048 + (size_t)lane * 8;
    const ushort* Wb = Wf + ((size_t)q * 162) * 8192 + (size_t)lane * 8 + (size_t)w * 1024;

    f32x16 acc00, acc01, acc10, acc11;
#pragma unroll
    for (int i = 0; i < 16; ++i) { acc00[i] = 0.f; acc01[i] = 0.f; acc10[i] = 0.f; acc11[i] = 0.f; }

    short8 ca0, ca1, ca2, ca3, cw0, cw1, cw2, cw3;   // A: hi0,hi1,lo0,lo1 ; W: hi n0, hi n1, lo n0, lo n1
    ca0 = *(const short8*)(Ab + 0);    ca1 = *(const short8*)(Ab + 512);
    ca2 = *(const short8*)(Ab + 1024); ca3 = *(const short8*)(Ab + 1536);
    cw0 = *(const short8*)(Wb + 0);    cw1 = *(const short8*)(Wb + 512);
    cw2 = *(const short8*)(Wb + 4096); cw3 = *(const short8*)(Wb + 4608);

    for (int ks = 0; ks < 162; ++ks) {
        short8 na0, na1, na2, na3, nw0, nw1, nw2, nw3;
        const bool pf = (ks < 161);
        if (pf) {
            const ushort* An = Ab + (size_t)(ks + 1) * 2048;
            const ushort* Wn = Wb + (size_t)(ks + 1) * 8192;
            na0 = *(const short8*)(An + 0);    na1 = *(const short8*)(An + 512);
            na2 = *(const short8*)(An + 1024); na3 = *(const short8*)(An + 1536);
            nw0 = *(const short8*)(Wn + 0);    nw1 = *(const short8*)(Wn + 512);
            nw2 = *(const short8*)(Wn + 4096); nw3 = *(const short8*)(Wn + 4608);
        }
        acc00 = MFMA32(ca0, cw0, acc00);
        acc00 = MFMA32(ca0, cw2, acc00);
        acc00 = MFMA32(ca2, cw0, acc00);
        acc01 = MFMA32(ca0, cw1, acc01);
        acc01 = MFMA32(ca0, cw3, acc01);
        acc01 = MFMA32(ca2, cw1, acc01);
        acc10 = MFMA32(ca1, cw0, acc10);
        acc10 = MFMA32(ca1, cw2, acc10);
        acc10 = MFMA32(ca3, cw0, acc10);
        acc11 = MFMA32(ca1, cw1, acc11);
        acc11 = MFMA32(ca1, cw3, acc11);
        acc11 = MFMA32(ca3, cw1, acc11);
        if (pf) {
            ca0 = na0; ca1 = na1; ca2 = na2; ca3 = na3;
            cw0 = nw0; cw1 = nw1; cw2 = nw2; cw3 = nw3;
        }
    }

    // epilogue: C[m][oc] -> part[q][b][cap][pos][d]
    const int l5 = lane >> 5, ln = lane & 31;
    float* pq = part + (size_t)q * 1179648;
#pragma unroll
    for (int mf = 0; mf < 2; ++mf) {
#pragma unroll
        for (int nf = 0; nf < 2; ++nf) {
            const f32x16 a = (mf == 0) ? (nf == 0 ? acc00 : acc01)
                                       : (nf == 0 ? acc10 : acc11);
            const int oc = (w * 2 + nf) * 32 + ln;
            float* pb = pq + (oc >> 3) * 288 + (oc & 7);
#pragma unroll
            for (int r = 0; r < 16; ++r) {
                const int m = mt * 64 + mf * 32 + (r & 3) + 8 * (r >> 2) + 4 * l5;
                const int b = m / 36;
                const int pos = m - b * 36;
                pb[(size_t)b * 9216 + pos * 8] = a[r];
            }
        }
    }
}

// ------------------------------- squash ------------------------------------
__global__ __launch_bounds__(256) void squash_kernel(
    const float* __restrict__ part, const float* __restrict__ bias,
    float* __restrict__ u, int nq)
{
    const int idx = blockIdx.x * 256 + threadIdx.x;
    if (idx >= 128 * 1152) return;
    const int i   = idx % 1152;
    const int cap = i / 36;
    float v[8];
    float n2 = 0.f;
#pragma unroll
    for (int c = 0; c < 8; ++c) {
        float s = bias[cap * 8 + c];
        for (int qq = 0; qq < nq; ++qq) s += part[(size_t)qq * 1179648 + (size_t)idx * 8 + c];
        v[c] = s;
        n2 += s * s;
    }
    const float sc = sqrtf(n2) / (1.f + n2);
#pragma unroll
    for (int c = 0; c < 8; ++c) u[(size_t)idx * 8 + c] = v[c] * sc;
}

// ------------------------------- routing -----------------------------------
__device__ __forceinline__ float4 uhat4(const float* __restrict__ urow,
                                        const float* __restrict__ wrow)
{
    float ur[8];
    const float4 u0 = *(const float4*)urow;
    const float4 u1 = *(const float4*)(urow + 4);
    ur[0] = u0.x; ur[1] = u0.y; ur[2] = u0.z; ur[3] = u0.w;
    ur[4] = u1.x; ur[5] = u1.y; ur[6] = u1.z; ur[7] = u1.w;
    float4 uh = make_float4(0.f, 0.f, 0.f, 0.f);
#pragma unroll
    for (int c = 0; c < 8; ++c) {
        const float4 wv = *(const float4*)(wrow + c * 16);
        uh.x += ur[c] * wv.x; uh.y += ur[c] * wv.y;
        uh.z += ur[c] * wv.z; uh.w += ur[c] * wv.w;
    }
    return uh;
}

__global__ __launch_bounds__(256) void routing_kernel(
    const float* __restrict__ u, const float* __restrict__ rw,
    float* __restrict__ out)
{
    const int b = blockIdx.x;
    const int o = blockIdx.y;
    const int t = threadIdx.x;
    __shared__ float logits[1152];
    __shared__ float ebuf[1152];
    __shared__ float psum[64][17];
    __shared__ float red[8];
    __shared__ float v_s[16];
    const float* ub = u + (size_t)b * 9216;
    const float* wo = rw + (size_t)o * 147456;
    for (int i = t; i < 1152; i += 256) logits[i] = 0.f;
    __syncthreads();
    const int dq = t & 3;
    const int ig = t >> 2;
    const int d4 = dq * 4;
    for (int iter = 1; iter <= 3; ++iter) {
        float lmax = -3.0e38f;
        for (int i = t; i < 1152; i += 256) lmax = fmaxf(lmax, logits[i]);
#pragma unroll
        for (int off = 32; off; off >>= 1) lmax = fmaxf(lmax, __shfl_xor(lmax, off, 64));
        if ((t & 63) == 0) red[t >> 6] = lmax;
        __syncthreads();
        const float m = fmaxf(fmaxf(red[0], red[1]), fmaxf(red[2], red[3]));
        float ls = 0.f;
        for (int i = t; i < 1152; i += 256) {
            const float e = expf(logits[i] - m);
            ebuf[i] = e;
            ls += e;
        }
#pragma unroll
        for (int off = 32; off; off >>= 1) ls += __shfl_xor(ls, off, 64);
        if ((t & 63) == 0) red[4 + (t >> 6)] = ls;
        __syncthreads();
        const float sumE = red[4] + red[5] + red[6] + red[7];
        float4 ps = make_float4(0.f, 0.f, 0.f, 0.f);
        for (int i = ig; i < 1152; i += 64) {
            const float4 uh = uhat4(ub + i * 8, wo + (size_t)i * 128 + d4);
            const float e = ebuf[i];
            ps.x += e * uh.x; ps.y += e * uh.y; ps.z += e * uh.z; ps.w += e * uh.w;
        }
        psum[ig][d4 + 0] = ps.x; psum[ig][d4 + 1] = ps.y;
        psum[ig][d4 + 2] = ps.z; psum[ig][d4 + 3] = ps.w;
        __syncthreads();
        if (t < 16) {
            float s = 0.f;
            for (int g = 0; g < 64; ++g) s += psum[g][t];
            s /= sumE;
            float qn = s * s;
            qn += __shfl_xor(qn, 1, 16); qn += __shfl_xor(qn, 2, 16);
            qn += __shfl_xor(qn, 4, 16); qn += __shfl_xor(qn, 8, 16);
            v_s[t] = s * sqrtf(qn) / (1.f + qn);
        }
        __syncthreads();
        if (iter < 3) {
            const float v0 = v_s[d4 + 0], v1 = v_s[d4 + 1];
            const float v2 = v_s[d4 + 2], v3 = v_s[d4 + 3];
            for (int i = ig; i < 1152; i += 64) {
                const float4 uh = uhat4(ub + i * 8, wo + (size_t)i * 128 + d4);
                float pr = uh.x * v0 + uh.y * v1 + uh.z * v2 + uh.w * v3;
                pr += __shfl_xor(pr, 1, 64);
                pr += __shfl_xor(pr, 2, 64);
                if (dq == 0) logits[i] += pr;
            }
            __syncthreads();
        }
    }
    if (t < 16) out[((size_t)b * 10 + o) * 16 + t] = v_s[t];
}

// ===================== FALLBACK (R5 fp32 direct conv) ======================
#define WSL4 1344

__device__ __forceinline__ void gl_lds16(const void* g, const void* lds_uniform_base) {
    __builtin_amdgcn_global_load_lds(
        (const __attribute__((address_space(1))) void*)g,
        (__attribute__((address_space(3))) void*)lds_uniform_base,
        16, 0, 0);
}

__global__ __launch_bounds__(256) void wtrans_kernel(
    const float* __restrict__ w, float* __restrict__ wT)
{
    const int idx = blockIdx.x * 256 + threadIdx.x;
    if (idx >= 4 * 256 * 81 * 16) return;
    const int c      = idx & 15;
    const int k      = (idx >> 4) % 81;
    const int ic     = ((idx >> 4) / 81) % 256;
    const int octile = idx / (16 * 81 * 256);
    const int ocb    = octile * 64 + c * 4;
    float4 v;
    v.x = w[((size_t)(ocb + 0) * 256 + ic) * 81 + k];
    v.y = w[((size_t)(ocb + 1) * 256 + ic) * 81 + k];
    v.z = w[((size_t)(ocb + 2) * 256 + ic) * 81 + k];
    v.w = w[((size_t)(ocb + 3) * 256 + ic) * 81 + k];
    ((float4*)wT)[((size_t)octile * 256 + ic) * WSL4 + k * 16 + c] = v;
}

__global__ __launch_bounds__(384) void pcaps_kernel(
    const float* __restrict__ x, const float* __restrict__ wT,
    float* __restrict__ part)
{
    const int btile  = blockIdx.x;
    const int octile = blockIdx.y;
    const int ict    = blockIdx.z;
    const int t    = threadIdx.x;
    const int wave = t >> 6;
    const int lane = t & 63;
    __shared__ float4 w_s[2][WSL4];
    __shared__ float4 x_s[2][448];
    const int oc4  = (t & 15) * 4;
    const int slot = t >> 4;
    const int bb   = slot / 6;
    const int oy   = slot - 6 * bb;
    const int b0   = btile * 4;
    float acc[6][4];
#pragma unroll
    for (int p = 0; p < 6; ++p) {
        acc[p][0] = 0.f; acc[p][1] = 0.f; acc[p][2] = 0.f; acc[p][3] = 0.f;
    }
    const float*  xg   = x + (size_t)b0 * 102400 + (size_t)ict * 25600;
    const float4* wsrc = (const float4*)wT + ((size_t)octile * 256 + ict * 64) * WSL4;
#define PCAPS_STAGE(bf_, ic_)                                                  \
    {                                                                          \
        const float4* gsl = wsrc + (size_t)(ic_) * WSL4;                       \
        for (int ch = wave; ch < 21; ch += 6)                                  \
            gl_lds16(gsl + ch * 64 + lane, &w_s[bf_][ch * 64]);                \
        for (int ch = wave; ch < 7; ch += 6) {                                 \
            int idx = ch * 64 + lane;                                          \
            if (idx >= 400) idx = 0;                                           \
            const int xbb = idx / 100;                                         \
            const int off = idx - xbb * 100;                                   \
            const float* g = xg + (size_t)xbb * 102400 + (ic_) * 400 + off * 4;\
            gl_lds16(g, &x_s[bf_][ch * 64]);                                   \
        }                                                                      \
    }
    PCAPS_STAGE(0, 0);
    __syncthreads();
    int buf = 0;
    for (int ic = 0; ic < 64; ++ic) {
        if (ic < 63) PCAPS_STAGE(buf ^ 1, ic + 1);
        const float* xrow = (const float*)x_s[buf] + bb * 400;
        const float* wrow = (const float*)w_s[buf];
#pragma unroll
        for (int ky = 0; ky < 9; ++ky) {
            float rowv[20];
            const float4* xr = (const float4*)&xrow[(2 * oy + ky) * 20];
#pragma unroll
            for (int j = 0; j < 5; ++j) ((float4*)rowv)[j] = xr[j];
#pragma unroll
            for (int kx = 0; kx < 9; ++kx) {
                const float4 wv = *(const float4*)&wrow[(ky * 9 + kx) * 64 + oc4];
#pragma unroll
                for (int p = 0; p < 6; ++p) {
                    const float xv = rowv[2 * p + kx];
                    acc[p][0] += xv * wv.x; acc[p][1] += xv * wv.y;
                    acc[p][2] += xv * wv.z; acc[p][3] += xv * wv.w;
                }
            }
        }
        __syncthreads();
        buf ^= 1;
    }
#undef PCAPS_STAGE
    float* pb = part + ((size_t)ict * 128 + (b0 + bb)) * 9216;
    const int oc0 = octile * 64 + oc4;
    const int cap = oc0 >> 3;
    const int d0  = oc0 & 7;
#pragma unroll
    for (int p = 0; p < 6; ++p) {
        const int pos = oy * 6 + p;
        *(float4*)&pb[((size_t)cap * 36 + pos) * 8 + d0] =
            make_float4(acc[p][0], acc[p][1], acc[p][2], acc[p][3]);
    }
}

// ------------------------------- launcher ----------------------------------
extern "C" void kernel_launch(void* const* d_in, const int* in_sizes, int n_in,
                              void* d_out, int out_size, void* d_ws, size_t ws_size,
                              hipStream_t stream)
{
    const float* img = (const float*)d_in[0];
    const float* c1w = (const float*)d_in[1];
    const float* c1b = (const float*)d_in[2];
    const float* pw  = (const float*)d_in[3];
    const float* pb  = (const float*)d_in[4];
    const float* rw  = (const float*)d_in[5];
    float* out = (float*)d_out;
    char* ws = (char*)d_ws;

    if (ws_size >= 498335744ULL) {
        // fast path: split-bf16 MFMA GEMM
        float*  x    = (float*)(ws);                       // 52,428,800 B
        float*  part = (float*)(ws + 52428800);            // 37,748,736 B (8 chunks)
        float*  u    = (float*)(ws + 90177536);            //  4,718,592 B
        ushort* Af   = (ushort*)(ws + 94896128);           // 382,205,952 B
        ushort* Wf   = (ushort*)(ws + 477102080);          // 21,233,664 B
        hipLaunchKernelGGL(conv1_kernel, dim3(4, 128), dim3(256), 0, stream, img, c1w, c1b, x);
        hipLaunchKernelGGL(wsplit_kernel, dim3(2592), dim3(256), 0, stream, pw, Wf);
        hipLaunchKernelGGL(im2col_kernel, dim3(46656), dim3(256), 0, stream, x, Af);
        hipLaunchKernelGGL(gemm_kernel, dim3(576), dim3(256), 0, stream, Af, Wf, part);
        hipLaunchKernelGGL(squash_kernel, dim3(576), dim3(256), 0, stream, part, pb, u, 8);
        hipLaunchKernelGGL(routing_kernel, dim3(128, 10), dim3(256), 0, stream, u, rw, out);
    } else {
        // fallback: R5 fp32 direct conv
        float* x    = (float*)(ws);
        float* part = (float*)(ws + 52428800);
        float* u    = (float*)(ws + 52428800 + 18874368);
        float* wT   = (float*)(ws + 52428800 + 18874368 + 4718592);
        hipLaunchKernelGGL(wtrans_kernel, dim3((4 * 256 * 81 * 16 + 255) / 256), dim3(256), 0, stream, pw, wT);
        hipLaunchKernelGGL(conv1_kernel, dim3(4, 128), dim3(256), 0, stream, img, c1w, c1b, x);
        hipLaunchKernelGGL(pcaps_kernel, dim3(32, 4, 4), dim3(384), 0, stream, x, wT, part);
        hipLaunchKernelGGL(squash_kernel, dim3(576), dim3(256), 0, stream, part, pb, u, 4);
        hipLaunchKernelGGL(routing_kernel, dim3(128, 10), dim3(256), 0, stream, u, rw, out);
    }
}

// Round 7
// 599.749 us; speedup vs baseline: 1.3784x; 1.3784x over previous
//
#include <hip/hip_runtime.h>
#include <hip/hip_bf16.h>
#include <math.h>

// ---------------------------------------------------------------------------
// CapsuleNetwork forward.
// FAST PATH (ws >= 126,091,264 B): pcaps conv = fused-im2col split-bf16 MFMA.
//   conv1  : img -> x[128,256,20,20] fp32
//   xsplit : x -> xT hi/lo bf16, channel-last [128][400 pos][256 ic]
//            (k-runs of 8 ic are 16B-contiguous -> A fragments load straight
//             from global, no im2col buffer)
//   wsplit : pcaps_w -> Wf hi/lo [81 tap][16 icstep][256 oc][16 ic] frag order
//   gemm2  : K-order = tap-major, ic-minor. 576 blocks = 72 mtiles x 8 tap
//            groups (q = bid&7 -> q-th XCD L2 owns its 2.7MB W chunk).
//            3-pass split (hi*hi + lo*hi + hi*lo), 32x32x16 bf16 MFMA,
//            no LDS / no barriers. part[8][...] split-K accumulate.
//   squash(nq=8) -> u ; routing -> out
// Aliasing: part+u live in the dead x region after xsplit.
// FALLBACK: R5 fp32 direct-conv path (proven 98 MB).
// ---------------------------------------------------------------------------

typedef __attribute__((ext_vector_type(8)))  short  short8;
typedef __attribute__((ext_vector_type(8)))  ushort ushort8v;
typedef __attribute__((ext_vector_type(16))) float  f32x16;
#define MFMA32(a, b, c) __builtin_amdgcn_mfma_f32_32x32x16_bf16(a, b, c, 0, 0, 0)

__device__ __forceinline__ void split_bf16(float v, ushort& h, ushort& l) {
    __hip_bfloat16 hb = __float2bfloat16(v);
    float hf = __bfloat162float(hb);
    __hip_bfloat16 lb = __float2bfloat16(v - hf);
    h = *reinterpret_cast<ushort*>(&hb);
    l = *reinterpret_cast<ushort*>(&lb);
}

// ------------------------------- conv1 -------------------------------------
__global__ __launch_bounds__(256) void conv1_kernel(
    const float* __restrict__ img, const float* __restrict__ w,
    const float* __restrict__ bias, float* __restrict__ x)
{
    const int ct = blockIdx.x;
    const int b  = blockIdx.y;
    const int t  = threadIdx.x;
    __shared__ float img_s[784];
    __shared__ float w_s[64 * 81];
    for (int idx = t; idx < 784; idx += 256) img_s[idx] = img[b * 784 + idx];
    for (int idx = t; idx < 64 * 81; idx += 256) w_s[idx] = w[ct * 64 * 81 + idx];
    __syncthreads();
    for (int task = t; task < 1280; task += 256) {
        const int cl = task / 20;
        const int oy = task - cl * 20;
        float acc[20];
        const float bv = bias[ct * 64 + cl];
#pragma unroll
        for (int j = 0; j < 20; ++j) acc[j] = bv;
#pragma unroll
        for (int ky = 0; ky < 9; ++ky) {
            float rowv[28];
            const float* r = &img_s[(oy + ky) * 28];
#pragma unroll
            for (int j = 0; j < 28; ++j) rowv[j] = r[j];
#pragma unroll
            for (int kx = 0; kx < 9; ++kx) {
                const float wv = w_s[cl * 81 + ky * 9 + kx];
#pragma unroll
                for (int j = 0; j < 20; ++j) acc[j] += wv * rowv[j + kx];
            }
        }
        float* xp = x + (((size_t)b * 256 + ct * 64 + cl) * 400) + oy * 20;
#pragma unroll
        for (int j = 0; j < 20; ++j) xp[j] = fmaxf(acc[j], 0.f);
    }
}

// ----------------------------- xsplit (fast) --------------------------------
// x[b][ic][p] fp32 -> xTh/xTl[b][p][ic] bf16 via LDS transpose (32-ic tiles).
__global__ __launch_bounds__(256) void xsplit_kernel(
    const float* __restrict__ x, ushort* __restrict__ xTh, ushort* __restrict__ xTl)
{
    const int b   = blockIdx.x;   // 128
    const int icb = blockIdx.y;   // 8 (32 ic each)
    const int t   = threadIdx.x;
    __shared__ float xs[32 * 401];
    const float* xb = x + ((size_t)b * 256 + icb * 32) * 400;
    for (int idx = t; idx < 12800; idx += 256) {
        const int ic = idx / 400;
        const int p  = idx - ic * 400;
        xs[ic * 401 + p] = xb[idx];
    }
    __syncthreads();
    for (int u = t; u < 1600; u += 256) {
        const int c = u / 400;          // 0..3 (8-ic chunk)
        const int p = u - c * 400;
        ushort8v h8, l8;
#pragma unroll
        for (int j = 0; j < 8; ++j) {
            ushort hb, lb;
            split_bf16(xs[(c * 8 + j) * 401 + p], hb, lb);
            h8[j] = hb; l8[j] = lb;
        }
        const size_t o = ((size_t)b * 400 + p) * 256 + icb * 32 + c * 8;
        *(ushort8v*)(xTh + o) = h8;
        *(ushort8v*)(xTl + o) = l8;
    }
}

// ----------------------------- wsplit (fast) --------------------------------
// pw[oc][ic][tap] -> Wfh/Wfl[tap][icstep][oc][16 ic] (B-fragment order).
__global__ __launch_bounds__(256) void wsplit_kernel(
    const float* __restrict__ pw, ushort* __restrict__ Wfh, ushort* __restrict__ Wfl)
{
    const int oc = blockIdx.x;    // 256
    const int t  = threadIdx.x;
    __shared__ float buf[1296];   // 16 ic x 81 tap
    const float* row = pw + (size_t)oc * 20736;
    for (int s = 0; s < 16; ++s) {
        __syncthreads();
        for (int idx = t; idx < 1296; idx += 256) buf[idx] = row[s * 1296 + idx];
        __syncthreads();
        if (t < 81) {
            const int tap = t;
            ushort8v h0, l0, h1, l1;
#pragma unroll
            for (int j = 0; j < 8; ++j) {
                ushort hb, lb;
                split_bf16(buf[j * 81 + tap], hb, lb);
                h0[j] = hb; l0[j] = lb;
                split_bf16(buf[(8 + j) * 81 + tap], hb, lb);
                h1[j] = hb; l1[j] = lb;
            }
            const size_t rec = (((size_t)tap * 16 + s) * 256 + oc) * 16;
            *(ushort8v*)(Wfh + rec)     = h0;
            *(ushort8v*)(Wfh + rec + 8) = h1;
            *(ushort8v*)(Wfl + rec)     = l0;
            *(ushort8v*)(Wfl + rec + 8) = l1;
        }
    }
}

// ------------------------------ gemm2 (fast) --------------------------------
// 576 blocks: q = bid&7 (tap group, XCD-resident W chunk), mt = bid>>3.
// 4 waves x 64 oc; per wave 2x2 frags of 32x32; A loads direct from global.
__global__ __launch_bounds__(256, 2) void gemm2_kernel(
    const ushort* __restrict__ xTh, const ushort* __restrict__ xTl,
    const ushort* __restrict__ Wfh, const ushort* __restrict__ Wfl,
    float* __restrict__ part)
{
    const int bid = blockIdx.x;
    const int q = bid & 7, mt = bid >> 3;
    const int t = threadIdx.x;
    const int w = t >> 6, lane = t & 63;
    const int ln = lane & 31, kh = (lane >> 5) * 8;
    const int ts = (q * 81) >> 3, te = ((q + 1) * 81) >> 3;

    const int m0 = mt * 64 + ln;
    const int b0 = m0 / 36, pos0 = m0 - b0 * 36;
    const int oy0 = pos0 / 6, ox0 = pos0 - oy0 * 6;
    const int m1 = m0 + 32;
    const int b1 = m1 / 36, pos1 = m1 - b1 * 36;
    const int oy1 = pos1 / 6, ox1 = pos1 - oy1 * 6;

    f32x16 acc00, acc01, acc10, acc11;
#pragma unroll
    for (int i = 0; i < 16; ++i) { acc00[i] = 0.f; acc01[i] = 0.f; acc10[i] = 0.f; acc11[i] = 0.f; }

    const size_t wofs = (((size_t)ts * 16) * 256 + w * 64 + ln) * 16 + kh;
    const ushort* wh = Wfh + wofs;
    const ushort* wl = Wfl + wofs;

    for (int tap = ts; tap < te; ++tap) {
        const int ky = tap / 9, kx = tap - ky * 9;
        const size_t a0 = ((size_t)b0 * 400 + (2 * oy0 + ky) * 20 + 2 * ox0 + kx) * 256 + kh;
        const size_t a1 = ((size_t)b1 * 400 + (2 * oy1 + ky) * 20 + 2 * ox1 + kx) * 256 + kh;
        const ushort* p0h = xTh + a0;  const ushort* p0l = xTl + a0;
        const ushort* p1h = xTh + a1;  const ushort* p1l = xTl + a1;
#pragma unroll 2
        for (int s = 0; s < 16; ++s) {
            const short8 a0h = *(const short8*)(p0h + s * 16);
            const short8 a1h = *(const short8*)(p1h + s * 16);
            const short8 a0l = *(const short8*)(p0l + s * 16);
            const short8 a1l = *(const short8*)(p1l + s * 16);
            const short8 w0h = *(const short8*)(wh);
            const short8 w1h = *(const short8*)(wh + 512);   // +32 oc
            const short8 w0l = *(const short8*)(wl);
            const short8 w1l = *(const short8*)(wl + 512);
            wh += 4096; wl += 4096;                          // next icstep
            acc00 = MFMA32(a0h, w0h, acc00);
            acc00 = MFMA32(a0l, w0h, acc00);
            acc00 = MFMA32(a0h, w0l, acc00);
            acc01 = MFMA32(a0h, w1h, acc01);
            acc01 = MFMA32(a0l, w1h, acc01);
            acc01 = MFMA32(a0h, w1l, acc01);
            acc10 = MFMA32(a1h, w0h, acc10);
            acc10 = MFMA32(a1l, w0h, acc10);
            acc10 = MFMA32(a1h, w0l, acc10);
            acc11 = MFMA32(a1h, w1h, acc11);
            acc11 = MFMA32(a1l, w1h, acc11);
            acc11 = MFMA32(a1h, w1l, acc11);
        }
    }

    // epilogue: C[m][oc] -> part[q][b][cap][pos][d]
    const int l5 = lane >> 5;
    float* pq = part + (size_t)q * 1179648;
#pragma unroll
    for (int mf = 0; mf < 2; ++mf) {
#pragma unroll
        for (int nf = 0; nf < 2; ++nf) {
            const f32x16 a = (mf == 0) ? (nf == 0 ? acc00 : acc01)
                                       : (nf == 0 ? acc10 : acc11);
            const int oc = w * 64 + nf * 32 + ln;
            float* pb = pq + (oc >> 3) * 288 + (oc & 7);
#pragma unroll
            for (int r = 0; r < 16; ++r) {
                const int m = mt * 64 + mf * 32 + (r & 3) + 8 * (r >> 2) + 4 * l5;
                const int b = m / 36;
                const int pos = m - b * 36;
                pb[(size_t)b * 9216 + pos * 8] = a[r];
            }
        }
    }
}

// ------------------------------- squash ------------------------------------
__global__ __launch_bounds__(256) void squash_kernel(
    const float* __restrict__ part, const float* __restrict__ bias,
    float* __restrict__ u, int nq)
{
    const int idx = blockIdx.x * 256 + threadIdx.x;
    if (idx >= 128 * 1152) return;
    const int i   = idx % 1152;
    const int cap = i / 36;
    float v[8];
    float n2 = 0.f;
#pragma unroll
    for (int c = 0; c < 8; ++c) {
        float s = bias[cap * 8 + c];
        for (int qq = 0; qq < nq; ++qq) s += part[(size_t)qq * 1179648 + (size_t)idx * 8 + c];
        v[c] = s;
        n2 += s * s;
    }
    const float sc = sqrtf(n2) / (1.f + n2);
#pragma unroll
    for (int c = 0; c < 8; ++c) u[(size_t)idx * 8 + c] = v[c] * sc;
}

// ------------------------------- routing -----------------------------------
__device__ __forceinline__ float4 uhat4(const float* __restrict__ urow,
                                        const float* __restrict__ wrow)
{
    float ur[8];
    const float4 u0 = *(const float4*)urow;
    const float4 u1 = *(const float4*)(urow + 4);
    ur[0] = u0.x; ur[1] = u0.y; ur[2] = u0.z; ur[3] = u0.w;
    ur[4] = u1.x; ur[5] = u1.y; ur[6] = u1.z; ur[7] = u1.w;
    float4 uh = make_float4(0.f, 0.f, 0.f, 0.f);
#pragma unroll
    for (int c = 0; c < 8; ++c) {
        const float4 wv = *(const float4*)(wrow + c * 16);
        uh.x += ur[c] * wv.x; uh.y += ur[c] * wv.y;
        uh.z += ur[c] * wv.z; uh.w += ur[c] * wv.w;
    }
    return uh;
}

__global__ __launch_bounds__(256) void routing_kernel(
    const float* __restrict__ u, const float* __restrict__ rw,
    float* __restrict__ out)
{
    const int b = blockIdx.x;
    const int o = blockIdx.y;
    const int t = threadIdx.x;
    __shared__ float logits[1152];
    __shared__ float ebuf[1152];
    __shared__ float psum[64][17];
    __shared__ float red[8];
    __shared__ float v_s[16];
    const float* ub = u + (size_t)b * 9216;
    const float* wo = rw + (size_t)o * 147456;
    for (int i = t; i < 1152; i += 256) logits[i] = 0.f;
    __syncthreads();
    const int dq = t & 3;
    const int ig = t >> 2;
    const int d4 = dq * 4;
    for (int iter = 1; iter <= 3; ++iter) {
        float lmax = -3.0e38f;
        for (int i = t; i < 1152; i += 256) lmax = fmaxf(lmax, logits[i]);
#pragma unroll
        for (int off = 32; off; off >>= 1) lmax = fmaxf(lmax, __shfl_xor(lmax, off, 64));
        if ((t & 63) == 0) red[t >> 6] = lmax;
        __syncthreads();
        const float m = fmaxf(fmaxf(red[0], red[1]), fmaxf(red[2], red[3]));
        float ls = 0.f;
        for (int i = t; i < 1152; i += 256) {
            const float e = expf(logits[i] - m);
            ebuf[i] = e;
            ls += e;
        }
#pragma unroll
        for (int off = 32; off; off >>= 1) ls += __shfl_xor(ls, off, 64);
        if ((t & 63) == 0) red[4 + (t >> 6)] = ls;
        __syncthreads();
        const float sumE = red[4] + red[5] + red[6] + red[7];
        float4 ps = make_float4(0.f, 0.f, 0.f, 0.f);
        for (int i = ig; i < 1152; i += 64) {
            const float4 uh = uhat4(ub + i * 8, wo + (size_t)i * 128 + d4);
            const float e = ebuf[i];
            ps.x += e * uh.x; ps.y += e * uh.y; ps.z += e * uh.z; ps.w += e * uh.w;
        }
        psum[ig][d4 + 0] = ps.x; psum[ig][d4 + 1] = ps.y;
        psum[ig][d4 + 2] = ps.z; psum[ig][d4 + 3] = ps.w;
        __syncthreads();
        if (t < 16) {
            float s = 0.f;
            for (int g = 0; g < 64; ++g) s += psum[g][t];
            s /= sumE;
            float qn = s * s;
            qn += __shfl_xor(qn, 1, 16); qn += __shfl_xor(qn, 2, 16);
            qn += __shfl_xor(qn, 4, 16); qn += __shfl_xor(qn, 8, 16);
            v_s[t] = s * sqrtf(qn) / (1.f + qn);
        }
        __syncthreads();
        if (iter < 3) {
            const float v0 = v_s[d4 + 0], v1 = v_s[d4 + 1];
            const float v2 = v_s[d4 + 2], v3 = v_s[d4 + 3];
            for (int i = ig; i < 1152; i += 64) {
                const float4 uh = uhat4(ub + i * 8, wo + (size_t)i * 128 + d4);
                float pr = uh.x * v0 + uh.y * v1 + uh.z * v2 + uh.w * v3;
                pr += __shfl_xor(pr, 1, 64);
                pr += __shfl_xor(pr, 2, 64);
                if (dq == 0) logits[i] += pr;
            }
            __syncthreads();
        }
    }
    if (t < 16) out[((size_t)b * 10 + o) * 16 + t] = v_s[t];
}

// ===================== FALLBACK (R5 fp32 direct conv) ======================
#define WSL4 1344

__device__ __forceinline__ void gl_lds16(const void* g, const void* lds_uniform_base) {
    __builtin_amdgcn_global_load_lds(
        (const __attribute__((address_space(1))) void*)g,
        (__attribute__((address_space(3))) void*)lds_uniform_base,
        16, 0, 0);
}

__global__ __launch_bounds__(256) void wtrans_kernel(
    const float* __restrict__ w, float* __restrict__ wT)
{
    const int idx = blockIdx.x * 256 + threadIdx.x;
    if (idx >= 4 * 256 * 81 * 16) return;
    const int c      = idx & 15;
    const int k      = (idx >> 4) % 81;
    const int ic     = ((idx >> 4) / 81) % 256;
    const int octile = idx / (16 * 81 * 256);
    const int ocb    = octile * 64 + c * 4;
    float4 v;
    v.x = w[((size_t)(ocb + 0) * 256 + ic) * 81 + k];
    v.y = w[((size_t)(ocb + 1) * 256 + ic) * 81 + k];
    v.z = w[((size_t)(ocb + 2) * 256 + ic) * 81 + k];
    v.w = w[((size_t)(ocb + 3) * 256 + ic) * 81 + k];
    ((float4*)wT)[((size_t)octile * 256 + ic) * WSL4 + k * 16 + c] = v;
}

__global__ __launch_bounds__(384) void pcaps_kernel(
    const float* __restrict__ x, const float* __restrict__ wT,
    float* __restrict__ part)
{
    const int btile  = blockIdx.x;
    const int octile = blockIdx.y;
    const int ict    = blockIdx.z;
    const int t    = threadIdx.x;
    const int wave = t >> 6;
    const int lane = t & 63;
    __shared__ float4 w_s[2][WSL4];
    __shared__ float4 x_s[2][448];
    const int oc4  = (t & 15) * 4;
    const int slot = t >> 4;
    const int bb   = slot / 6;
    const int oy   = slot - 6 * bb;
    const int b0   = btile * 4;
    float acc[6][4];
#pragma unroll
    for (int p = 0; p < 6; ++p) {
        acc[p][0] = 0.f; acc[p][1] = 0.f; acc[p][2] = 0.f; acc[p][3] = 0.f;
    }
    const float*  xg   = x + (size_t)b0 * 102400 + (size_t)ict * 25600;
    const float4* wsrc = (const float4*)wT + ((size_t)octile * 256 + ict * 64) * WSL4;
#define PCAPS_STAGE(bf_, ic_)                                                  \
    {                                                                          \
        const float4* gsl = wsrc + (size_t)(ic_) * WSL4;                       \
        for (int ch = wave; ch < 21; ch += 6)                                  \
            gl_lds16(gsl + ch * 64 + lane, &w_s[bf_][ch * 64]);                \
        for (int ch = wave; ch < 7; ch += 6) {                                 \
            int idx = ch * 64 + lane;                                          \
            if (idx >= 400) idx = 0;                                           \
            const int xbb = idx / 100;                                         \
            const int off = idx - xbb * 100;                                   \
            const float* g = xg + (size_t)xbb * 102400 + (ic_) * 400 + off * 4;\
            gl_lds16(g, &x_s[bf_][ch * 64]);                                   \
        }                                                                      \
    }
    PCAPS_STAGE(0, 0);
    __syncthreads();
    int buf = 0;
    for (int ic = 0; ic < 64; ++ic) {
        if (ic < 63) PCAPS_STAGE(buf ^ 1, ic + 1);
        const float* xrow = (const float*)x_s[buf] + bb * 400;
        const float* wrow = (const float*)w_s[buf];
#pragma unroll
        for (int ky = 0; ky < 9; ++ky) {
            float rowv[20];
            const float4* xr = (const float4*)&xrow[(2 * oy + ky) * 20];
#pragma unroll
            for (int j = 0; j < 5; ++j) ((float4*)rowv)[j] = xr[j];
#pragma unroll
            for (int kx = 0; kx < 9; ++kx) {
                const float4 wv = *(const float4*)&wrow[(ky * 9 + kx) * 64 + oc4];
#pragma unroll
                for (int p = 0; p < 6; ++p) {
                    const float xv = rowv[2 * p + kx];
                    acc[p][0] += xv * wv.x; acc[p][1] += xv * wv.y;
                    acc[p][2] += xv * wv.z; acc[p][3] += xv * wv.w;
                }
            }
        }
        __syncthreads();
        buf ^= 1;
    }
#undef PCAPS_STAGE
    float* pb = part + ((size_t)ict * 128 + (b0 + bb)) * 9216;
    const int oc0 = octile * 64 + oc4;
    const int cap = oc0 >> 3;
    const int d0  = oc0 & 7;
#pragma unroll
    for (int p = 0; p < 6; ++p) {
        const int pos = oy * 6 + p;
        *(float4*)&pb[((size_t)cap * 36 + pos) * 8 + d0] =
            make_float4(acc[p][0], acc[p][1], acc[p][2], acc[p][3]);
    }
}

// ------------------------------- launcher ----------------------------------
extern "C" void kernel_launch(void* const* d_in, const int* in_sizes, int n_in,
                              void* d_out, int out_size, void* d_ws, size_t ws_size,
                              hipStream_t stream)
{
    const float* img = (const float*)d_in[0];
    const float* c1w = (const float*)d_in[1];
    const float* c1b = (const float*)d_in[2];
    const float* pw  = (const float*)d_in[3];
    const float* pb  = (const float*)d_in[4];
    const float* rw  = (const float*)d_in[5];
    float* out = (float*)d_out;
    char* ws = (char*)d_ws;

    if (ws_size >= 126091264ULL) {
        // fast path: fused-im2col split-bf16 MFMA GEMM (126.09 MB)
        float*  x    = (float*)(ws);                  // 52,428,800 B (dead after xsplit)
        float*  part = (float*)(ws);                  // 37,748,736 B (aliases x)
        float*  u    = (float*)(ws + 37748736);       //  4,718,592 B (aliases x)
        ushort* xTh  = (ushort*)(ws + 52428800);      // 26,214,400 B
        ushort* xTl  = (ushort*)(ws + 78643200);      // 26,214,400 B
        ushort* Wfh  = (ushort*)(ws + 104857600);     // 10,616,832 B
        ushort* Wfl  = (ushort*)(ws + 115474432);     // 10,616,832 B
        hipLaunchKernelGGL(conv1_kernel, dim3(4, 128), dim3(256), 0, stream, img, c1w, c1b, x);
        hipLaunchKernelGGL(xsplit_kernel, dim3(128, 8), dim3(256), 0, stream, x, xTh, xTl);
        hipLaunchKernelGGL(wsplit_kernel, dim3(256), dim3(256), 0, stream, pw, Wfh, Wfl);
        hipLaunchKernelGGL(gemm2_kernel, dim3(576), dim3(256), 0, stream, xTh, xTl, Wfh, Wfl, part);
        hipLaunchKernelGGL(squash_kernel, dim3(576), dim3(256), 0, stream, part, pb, u, 8);
        hipLaunchKernelGGL(routing_kernel, dim3(128, 10), dim3(256), 0, stream, u, rw, out);
    } else {
        // fallback: R5 fp32 direct conv (97.9 MB, proven)
        float* x    = (float*)(ws);
        float* part = (float*)(ws + 52428800);
        float* u    = (float*)(ws + 52428800 + 18874368);
        float* wT   = (float*)(ws + 52428800 + 18874368 + 4718592);
        hipLaunchKernelGGL(wtrans_kernel, dim3((4 * 256 * 81 * 16 + 255) / 256), dim3(256), 0, stream, pw, wT);
        hipLaunchKernelGGL(conv1_kernel, dim3(4, 128), dim3(256), 0, stream, img, c1w, c1b, x);
        hipLaunchKernelGGL(pcaps_kernel, dim3(32, 4, 4), dim3(384), 0, stream, x, wT, part);
        hipLaunchKernelGGL(squash_kernel, dim3(576), dim3(256), 0, stream, part, pb, u, 4);
        hipLaunchKernelGGL(routing_kernel, dim3(128, 10), dim3(256), 0, stream, u, rw, out);
    }
}

// Round 8
// 496.831 us; speedup vs baseline: 1.6639x; 1.2071x over previous
//
#include <hip/hip_runtime.h>
#include <hip/hip_bf16.h>
#include <math.h>

// ---------------------------------------------------------------------------
// CapsuleNetwork forward.
// FAST PATH (ws >= 126,091,264 B): pcaps conv = fused-im2col split-bf16 MFMA.
//   conv1  : img -> x[128,256,20,20] fp32
//   xsplit : x -> xT hi/lo bf16, channel-last [128][400 pos][256 ic]
//   wsplit : pcaps_w -> Wf hi/lo [81 tap][16 icstep][256 oc][16 ic] frag order
//   gemm3  : 1152 blocks = 144 mtiles(32 rows) x 8 tap groups (q=bid&7 ->
//            XCD-resident W chunk). Explicit branchless register double-buffer
//            (prefetch it+1 fragments before it's 6 MFMAs). 3-pass split bf16.
//   squash(nq=8) -> u ; routing v2 (u_hat cached in LDS bf16) -> out
// FALLBACK: R5 fp32 direct-conv path.
// ---------------------------------------------------------------------------

typedef __attribute__((ext_vector_type(8)))  short  short8;
typedef __attribute__((ext_vector_type(8)))  ushort ushort8v;
typedef __attribute__((ext_vector_type(16))) float  f32x16;
#define MFMA32(a, b, c) __builtin_amdgcn_mfma_f32_32x32x16_bf16(a, b, c, 0, 0, 0)

__device__ __forceinline__ void split_bf16(float v, ushort& h, ushort& l) {
    __hip_bfloat16 hb = __float2bfloat16(v);
    float hf = __bfloat162float(hb);
    __hip_bfloat16 lb = __float2bfloat16(v - hf);
    h = *reinterpret_cast<ushort*>(&hb);
    l = *reinterpret_cast<ushort*>(&lb);
}

// ------------------------------- conv1 -------------------------------------
__global__ __launch_bounds__(256) void conv1_kernel(
    const float* __restrict__ img, const float* __restrict__ w,
    const float* __restrict__ bias, float* __restrict__ x)
{
    const int ct = blockIdx.x;
    const int b  = blockIdx.y;
    const int t  = threadIdx.x;
    __shared__ float img_s[784];
    __shared__ float w_s[64 * 81];
    for (int idx = t; idx < 784; idx += 256) img_s[idx] = img[b * 784 + idx];
    for (int idx = t; idx < 64 * 81; idx += 256) w_s[idx] = w[ct * 64 * 81 + idx];
    __syncthreads();
    for (int task = t; task < 1280; task += 256) {
        const int cl = task / 20;
        const int oy = task - cl * 20;
        float acc[20];
        const float bv = bias[ct * 64 + cl];
#pragma unroll
        for (int j = 0; j < 20; ++j) acc[j] = bv;
#pragma unroll
        for (int ky = 0; ky < 9; ++ky) {
            float rowv[28];
            const float* r = &img_s[(oy + ky) * 28];
#pragma unroll
            for (int j = 0; j < 28; ++j) rowv[j] = r[j];
#pragma unroll
            for (int kx = 0; kx < 9; ++kx) {
                const float wv = w_s[cl * 81 + ky * 9 + kx];
#pragma unroll
                for (int j = 0; j < 20; ++j) acc[j] += wv * rowv[j + kx];
            }
        }
        float* xp = x + (((size_t)b * 256 + ct * 64 + cl) * 400) + oy * 20;
#pragma unroll
        for (int j = 0; j < 20; ++j) xp[j] = fmaxf(acc[j], 0.f);
    }
}

// ----------------------------- xsplit (fast) --------------------------------
__global__ __launch_bounds__(256) void xsplit_kernel(
    const float* __restrict__ x, ushort* __restrict__ xTh, ushort* __restrict__ xTl)
{
    const int b   = blockIdx.x;   // 128
    const int icb = blockIdx.y;   // 8 (32 ic each)
    const int t   = threadIdx.x;
    __shared__ float xs[32 * 401];
    const float* xb = x + ((size_t)b * 256 + icb * 32) * 400;
    for (int idx = t; idx < 12800; idx += 256) {
        const int ic = idx / 400;
        const int p  = idx - ic * 400;
        xs[ic * 401 + p] = xb[idx];
    }
    __syncthreads();
    for (int u = t; u < 1600; u += 256) {
        const int c = u / 400;
        const int p = u - c * 400;
        ushort8v h8, l8;
#pragma unroll
        for (int j = 0; j < 8; ++j) {
            ushort hb, lb;
            split_bf16(xs[(c * 8 + j) * 401 + p], hb, lb);
            h8[j] = hb; l8[j] = lb;
        }
        const size_t o = ((size_t)b * 400 + p) * 256 + icb * 32 + c * 8;
        *(ushort8v*)(xTh + o) = h8;
        *(ushort8v*)(xTl + o) = l8;
    }
}

// ----------------------------- wsplit (fast) --------------------------------
__global__ __launch_bounds__(256) void wsplit_kernel(
    const float* __restrict__ pw, ushort* __restrict__ Wfh, ushort* __restrict__ Wfl)
{
    const int oc = blockIdx.x;    // 256
    const int t  = threadIdx.x;
    __shared__ float buf[1296];
    const float* row = pw + (size_t)oc * 20736;
    for (int s = 0; s < 16; ++s) {
        __syncthreads();
        for (int idx = t; idx < 1296; idx += 256) buf[idx] = row[s * 1296 + idx];
        __syncthreads();
        if (t < 81) {
            const int tap = t;
            ushort8v h0, l0, h1, l1;
#pragma unroll
            for (int j = 0; j < 8; ++j) {
                ushort hb, lb;
                split_bf16(buf[j * 81 + tap], hb, lb);
                h0[j] = hb; l0[j] = lb;
                split_bf16(buf[(8 + j) * 81 + tap], hb, lb);
                h1[j] = hb; l1[j] = lb;
            }
            const size_t rec = (((size_t)tap * 16 + s) * 256 + oc) * 16;
            *(ushort8v*)(Wfh + rec)     = h0;
            *(ushort8v*)(Wfh + rec + 8) = h1;
            *(ushort8v*)(Wfl + rec)     = l0;
            *(ushort8v*)(Wfl + rec + 8) = l1;
        }
    }
}

// ------------------------------ gemm3 (fast) --------------------------------
// 1152 blocks: q = bid&7, mt = bid>>3 (32-row M tile). 4 waves x 64 oc each.
// Register double-buffer: prefetch it+1's 6 fragments before it's 6 MFMAs.
__global__ __launch_bounds__(256, 4) void gemm3_kernel(
    const ushort* __restrict__ xTh, const ushort* __restrict__ xTl,
    const ushort* __restrict__ Wfh, const ushort* __restrict__ Wfl,
    float* __restrict__ part)
{
    const int bid = blockIdx.x;
    const int q = bid & 7, mt = bid >> 3;
    const int t = threadIdx.x;
    const int w = t >> 6, lane = t & 63;
    const int ln = lane & 31, kh = (lane >> 5) * 8;
    const int ts = (q * 81) >> 3, te = ((q + 1) * 81) >> 3;

    const int m0 = mt * 32 + ln;
    const int b0 = m0 / 36, pos0 = m0 - b0 * 36;
    const int oy0 = pos0 / 6, ox0 = pos0 - oy0 * 6;

    f32x16 acc0, acc1;
#pragma unroll
    for (int i = 0; i < 16; ++i) { acc0[i] = 0.f; acc1[i] = 0.f; }

    const ushort* wh = Wfh + (((size_t)ts * 16) * 256 + w * 64 + ln) * 16 + kh;
    const ushort* wl = Wfl + (((size_t)ts * 16) * 256 + w * 64 + ln) * 16 + kh;

    {
        const int ky = ts / 9, kx = ts - 9 * (ts / 9);
        const size_t a0 = ((size_t)b0 * 400 + (2 * oy0 + ky) * 20 + 2 * ox0 + kx) * 256 + kh;
        // current A row pointers
        const ushort* phc = xTh + a0;
        const ushort* plc = xTl + a0;
        // current fragment registers
        short8 cah  = *(const short8*)(phc);
        short8 cal  = *(const short8*)(plc);
        short8 cw0h = *(const short8*)(wh);
        short8 cw1h = *(const short8*)(wh + 512);
        short8 cw0l = *(const short8*)(wl);
        short8 cw1l = *(const short8*)(wl + 512);

        for (int tap = ts; tap < te; ++tap) {
            const int tapn = (tap + 1 < te) ? tap + 1 : tap;
            const int kyn = tapn / 9, kxn = tapn - 9 * kyn;
            const size_t an = ((size_t)b0 * 400 + (2 * oy0 + kyn) * 20 + 2 * ox0 + kxn) * 256 + kh;
            const ushort* pnh = xTh + an;
            const ushort* pnl = xTl + an;
            const size_t wlast = (tap + 1 < te) ? 4096 : 0;
#pragma unroll
            for (int s = 0; s < 16; ++s) {
                const size_t wstep = (s < 15) ? (size_t)4096 : wlast;
                const short8 nah  = *(const short8*)((s < 15) ? phc + (s + 1) * 16 : pnh);
                const short8 nal  = *(const short8*)((s < 15) ? plc + (s + 1) * 16 : pnl);
                const short8 nw0h = *(const short8*)(wh + wstep);
                const short8 nw1h = *(const short8*)(wh + wstep + 512);
                const short8 nw0l = *(const short8*)(wl + wstep);
                const short8 nw1l = *(const short8*)(wl + wstep + 512);
                acc0 = MFMA32(cah, cw0h, acc0);
                acc0 = MFMA32(cal, cw0h, acc0);
                acc0 = MFMA32(cah, cw0l, acc0);
                acc1 = MFMA32(cah, cw1h, acc1);
                acc1 = MFMA32(cal, cw1h, acc1);
                acc1 = MFMA32(cah, cw1l, acc1);
                cah = nah; cal = nal;
                cw0h = nw0h; cw1h = nw1h; cw0l = nw0l; cw1l = nw1l;
                wh += wstep; wl += wstep;
            }
            phc = pnh; plc = pnl;
        }
    }

    // epilogue: C[m][oc] -> part[q][b][cap][pos][d]
    const int l5 = lane >> 5;
    float* pq = part + (size_t)q * 1179648;
#pragma unroll
    for (int nf = 0; nf < 2; ++nf) {
        const f32x16 a = nf ? acc1 : acc0;
        const int oc = w * 64 + nf * 32 + ln;
        float* pb = pq + (oc >> 3) * 288 + (oc & 7);
#pragma unroll
        for (int r = 0; r < 16; ++r) {
            const int m = mt * 32 + (r & 3) + 8 * (r >> 2) + 4 * l5;
            const int b = m / 36;
            const int pos = m - b * 36;
            pb[(size_t)b * 9216 + pos * 8] = a[r];
        }
    }
}

// ------------------------------- squash ------------------------------------
__global__ __launch_bounds__(256) void squash_kernel(
    const float* __restrict__ part, const float* __restrict__ bias,
    float* __restrict__ u, int nq)
{
    const int idx = blockIdx.x * 256 + threadIdx.x;
    if (idx >= 128 * 1152) return;
    const int i   = idx % 1152;
    const int cap = i / 36;
    float v[8];
    float n2 = 0.f;
#pragma unroll
    for (int c = 0; c < 8; ++c) {
        float s = bias[cap * 8 + c];
        for (int qq = 0; qq < nq; ++qq) s += part[(size_t)qq * 1179648 + (size_t)idx * 8 + c];
        v[c] = s;
        n2 += s * s;
    }
    const float sc = sqrtf(n2) / (1.f + n2);
#pragma unroll
    for (int c = 0; c < 8; ++c) u[(size_t)idx * 8 + c] = v[c] * sc;
}

// ------------------------------- routing v2 --------------------------------
__device__ __forceinline__ float4 uhat4(const float* __restrict__ urow,
                                        const float* __restrict__ wrow)
{
    float ur[8];
    const float4 u0 = *(const float4*)urow;
    const float4 u1 = *(const float4*)(urow + 4);
    ur[0] = u0.x; ur[1] = u0.y; ur[2] = u0.z; ur[3] = u0.w;
    ur[4] = u1.x; ur[5] = u1.y; ur[6] = u1.z; ur[7] = u1.w;
    float4 uh = make_float4(0.f, 0.f, 0.f, 0.f);
#pragma unroll
    for (int c = 0; c < 8; ++c) {
        const float4 wv = *(const float4*)(wrow + c * 16);
        uh.x += ur[c] * wv.x; uh.y += ur[c] * wv.y;
        uh.z += ur[c] * wv.z; uh.w += ur[c] * wv.w;
    }
    return uh;
}

__device__ __forceinline__ float4 uh_from_lds(const ushort* uhs, int i, int d4)
{
    const uint2 rv = *(const uint2*)(uhs + i * 16 + d4);
    float4 r;
    r.x = __uint_as_float((rv.x & 0xffffu) << 16);
    r.y = __uint_as_float((rv.x >> 16) << 16);
    r.z = __uint_as_float((rv.y & 0xffffu) << 16);
    r.w = __uint_as_float((rv.y >> 16) << 16);
    return r;
}

__global__ __launch_bounds__(256) void routing_kernel(
    const float* __restrict__ u, const float* __restrict__ rw,
    float* __restrict__ out)
{
    const int b = blockIdx.x;
    const int o = blockIdx.y;
    const int t = threadIdx.x;
    __shared__ ushort uh_s[1152 * 16];   // u_hat cached bf16 (36,864 B)
    __shared__ float logits[1152];
    __shared__ float ebuf[1152];
    __shared__ float psum[64][17];
    __shared__ float red[8];
    __shared__ float v_s[16];
    const float* ub = u + (size_t)b * 9216;
    const float* wo = rw + (size_t)o * 147456;
    for (int i = t; i < 1152; i += 256) logits[i] = 0.f;
    __syncthreads();
    const int dq = t & 3;
    const int ig = t >> 2;
    const int d4 = dq * 4;
    for (int iter = 1; iter <= 3; ++iter) {
        float lmax = -3.0e38f;
        for (int i = t; i < 1152; i += 256) lmax = fmaxf(lmax, logits[i]);
#pragma unroll
        for (int off = 32; off; off >>= 1) lmax = fmaxf(lmax, __shfl_xor(lmax, off, 64));
        if ((t & 63) == 0) red[t >> 6] = lmax;
        __syncthreads();
        const float m = fmaxf(fmaxf(red[0], red[1]), fmaxf(red[2], red[3]));
        float ls = 0.f;
        for (int i = t; i < 1152; i += 256) {
            const float e = expf(logits[i] - m);
            ebuf[i] = e;
            ls += e;
        }
#pragma unroll
        for (int off = 32; off; off >>= 1) ls += __shfl_xor(ls, off, 64);
        if ((t & 63) == 0) red[4 + (t >> 6)] = ls;
        __syncthreads();
        const float sumE = red[4] + red[5] + red[6] + red[7];
        float4 ps = make_float4(0.f, 0.f, 0.f, 0.f);
        if (iter == 1) {
            // compute u_hat from global, cache bf16 in LDS
            for (int i = ig; i < 1152; i += 64) {
                const float4 uh = uhat4(ub + i * 8, wo + (size_t)i * 128 + d4);
                ushort4 hb;
                __hip_bfloat16 q0 = __float2bfloat16(uh.x);
                __hip_bfloat16 q1 = __float2bfloat16(uh.y);
                __hip_bfloat16 q2 = __float2bfloat16(uh.z);
                __hip_bfloat16 q3 = __float2bfloat16(uh.w);
                hb.x = *(ushort*)&q0; hb.y = *(ushort*)&q1;
                hb.z = *(ushort*)&q2; hb.w = *(ushort*)&q3;
                *(ushort4*)(uh_s + i * 16 + d4) = hb;
                const float e = ebuf[i];
                ps.x += e * uh.x; ps.y += e * uh.y; ps.z += e * uh.z; ps.w += e * uh.w;
            }
        } else {
            for (int i = ig; i < 1152; i += 64) {
                const float4 uh = uh_from_lds(uh_s, i, d4);
                const float e = ebuf[i];
                ps.x += e * uh.x; ps.y += e * uh.y; ps.z += e * uh.z; ps.w += e * uh.w;
            }
        }
        psum[ig][d4 + 0] = ps.x; psum[ig][d4 + 1] = ps.y;
        psum[ig][d4 + 2] = ps.z; psum[ig][d4 + 3] = ps.w;
        __syncthreads();
        if (t < 16) {
            float s = 0.f;
            for (int g = 0; g < 64; ++g) s += psum[g][t];
            s /= sumE;
            float qn = s * s;
            qn += __shfl_xor(qn, 1, 16); qn += __shfl_xor(qn, 2, 16);
            qn += __shfl_xor(qn, 4, 16); qn += __shfl_xor(qn, 8, 16);
            v_s[t] = s * sqrtf(qn) / (1.f + qn);
        }
        __syncthreads();
        if (iter < 3) {
            const float v0 = v_s[d4 + 0], v1 = v_s[d4 + 1];
            const float v2 = v_s[d4 + 2], v3 = v_s[d4 + 3];
            for (int i = ig; i < 1152; i += 64) {
                const float4 uh = uh_from_lds(uh_s, i, d4);
                float pr = uh.x * v0 + uh.y * v1 + uh.z * v2 + uh.w * v3;
                pr += __shfl_xor(pr, 1, 64);
                pr += __shfl_xor(pr, 2, 64);
                if (dq == 0) logits[i] += pr;
            }
            __syncthreads();
        }
    }
    if (t < 16) out[((size_t)b * 10 + o) * 16 + t] = v_s[t];
}

// ===================== FALLBACK (R5 fp32 direct conv) ======================
#define WSL4 1344

__device__ __forceinline__ void gl_lds16(const void* g, const void* lds_uniform_base) {
    __builtin_amdgcn_global_load_lds(
        (const __attribute__((address_space(1))) void*)g,
        (__attribute__((address_space(3))) void*)lds_uniform_base,
        16, 0, 0);
}

__global__ __launch_bounds__(256) void wtrans_kernel(
    const float* __restrict__ w, float* __restrict__ wT)
{
    const int idx = blockIdx.x * 256 + threadIdx.x;
    if (idx >= 4 * 256 * 81 * 16) return;
    const int c      = idx & 15;
    const int k      = (idx >> 4) % 81;
    const int ic     = ((idx >> 4) / 81) % 256;
    const int octile = idx / (16 * 81 * 256);
    const int ocb    = octile * 64 + c * 4;
    float4 v;
    v.x = w[((size_t)(ocb + 0) * 256 + ic) * 81 + k];
    v.y = w[((size_t)(ocb + 1) * 256 + ic) * 81 + k];
    v.z = w[((size_t)(ocb + 2) * 256 + ic) * 81 + k];
    v.w = w[((size_t)(ocb + 3) * 256 + ic) * 81 + k];
    ((float4*)wT)[((size_t)octile * 256 + ic) * WSL4 + k * 16 + c] = v;
}

__global__ __launch_bounds__(384) void pcaps_kernel(
    const float* __restrict__ x, const float* __restrict__ wT,
    float* __restrict__ part)
{
    const int btile  = blockIdx.x;
    const int octile = blockIdx.y;
    const int ict    = blockIdx.z;
    const int t    = threadIdx.x;
    const int wave = t >> 6;
    const int lane = t & 63;
    __shared__ float4 w_s[2][WSL4];
    __shared__ float4 x_s[2][448];
    const int oc4  = (t & 15) * 4;
    const int slot = t >> 4;
    const int bb   = slot / 6;
    const int oy   = slot - 6 * bb;
    const int b0   = btile * 4;
    float acc[6][4];
#pragma unroll
    for (int p = 0; p < 6; ++p) {
        acc[p][0] = 0.f; acc[p][1] = 0.f; acc[p][2] = 0.f; acc[p][3] = 0.f;
    }
    const float*  xg   = x + (size_t)b0 * 102400 + (size_t)ict * 25600;
    const float4* wsrc = (const float4*)wT + ((size_t)octile * 256 + ict * 64) * WSL4;
#define PCAPS_STAGE(bf_, ic_)                                                  \
    {                                                                          \
        const float4* gsl = wsrc + (size_t)(ic_) * WSL4;                       \
        for (int ch = wave; ch < 21; ch += 6)                                  \
            gl_lds16(gsl + ch * 64 + lane, &w_s[bf_][ch * 64]);                \
        for (int ch = wave; ch < 7; ch += 6) {                                 \
            int idx = ch * 64 + lane;                                          \
            if (idx >= 400) idx = 0;                                           \
            const int xbb = idx / 100;                                         \
            const int off = idx - xbb * 100;                                   \
            const float* g = xg + (size_t)xbb * 102400 + (ic_) * 400 + off * 4;\
            gl_lds16(g, &x_s[bf_][ch * 64]);                                   \
        }                                                                      \
    }
    PCAPS_STAGE(0, 0);
    __syncthreads();
    int buf = 0;
    for (int ic = 0; ic < 64; ++ic) {
        if (ic < 63) PCAPS_STAGE(buf ^ 1, ic + 1);
        const float* xrow = (const float*)x_s[buf] + bb * 400;
        const float* wrow = (const float*)w_s[buf];
#pragma unroll
        for (int ky = 0; ky < 9; ++ky) {
            float rowv[20];
            const float4* xr = (const float4*)&xrow[(2 * oy + ky) * 20];
#pragma unroll
            for (int j = 0; j < 5; ++j) ((float4*)rowv)[j] = xr[j];
#pragma unroll
            for (int kx = 0; kx < 9; ++kx) {
                const float4 wv = *(const float4*)&wrow[(ky * 9 + kx) * 64 + oc4];
#pragma unroll
                for (int p = 0; p < 6; ++p) {
                    const float xv = rowv[2 * p + kx];
                    acc[p][0] += xv * wv.x; acc[p][1] += xv * wv.y;
                    acc[p][2] += xv * wv.z; acc[p][3] += xv * wv.w;
                }
            }
        }
        __syncthreads();
        buf ^= 1;
    }
#undef PCAPS_STAGE
    float* pb = part + ((size_t)ict * 128 + (b0 + bb)) * 9216;
    const int oc0 = octile * 64 + oc4;
    const int cap = oc0 >> 3;
    const int d0  = oc0 & 7;
#pragma unroll
    for (int p = 0; p < 6; ++p) {
        const int pos = oy * 6 + p;
        *(float4*)&pb[((size_t)cap * 36 + pos) * 8 + d0] =
            make_float4(acc[p][0], acc[p][1], acc[p][2], acc[p][3]);
    }
}

// ------------------------------- launcher ----------------------------------
extern "C" void kernel_launch(void* const* d_in, const int* in_sizes, int n_in,
                              void* d_out, int out_size, void* d_ws, size_t ws_size,
                              hipStream_t stream)
{
    const float* img = (const float*)d_in[0];
    const float* c1w = (const float*)d_in[1];
    const float* c1b = (const float*)d_in[2];
    const float* pw  = (const float*)d_in[3];
    const float* pb  = (const float*)d_in[4];
    const float* rw  = (const float*)d_in[5];
    float* out = (float*)d_out;
    char* ws = (char*)d_ws;

    if (ws_size >= 126091264ULL) {
        // fast path: fused-im2col split-bf16 MFMA GEMM (126.09 MB)
        float*  x    = (float*)(ws);                  // 52,428,800 B (dead after xsplit)
        float*  part = (float*)(ws);                  // 37,748,736 B (aliases x)
        float*  u    = (float*)(ws + 37748736);       //  4,718,592 B (aliases x)
        ushort* xTh  = (ushort*)(ws + 52428800);      // 26,214,400 B
        ushort* xTl  = (ushort*)(ws + 78643200);      // 26,214,400 B
        ushort* Wfh  = (ushort*)(ws + 104857600);     // 10,616,832 B
        ushort* Wfl  = (ushort*)(ws + 115474432);     // 10,616,832 B
        hipLaunchKernelGGL(conv1_kernel, dim3(4, 128), dim3(256), 0, stream, img, c1w, c1b, x);
        hipLaunchKernelGGL(xsplit_kernel, dim3(128, 8), dim3(256), 0, stream, x, xTh, xTl);
        hipLaunchKernelGGL(wsplit_kernel, dim3(256), dim3(256), 0, stream, pw, Wfh, Wfl);
        hipLaunchKernelGGL(gemm3_kernel, dim3(1152), dim3(256), 0, stream, xTh, xTl, Wfh, Wfl, part);
        hipLaunchKernelGGL(squash_kernel, dim3(576), dim3(256), 0, stream, part, pb, u, 8);
        hipLaunchKernelGGL(routing_kernel, dim3(128, 10), dim3(256), 0, stream, u, rw, out);
    } else {
        // fallback: R5 fp32 direct conv (97.9 MB, proven)
        float* x    = (float*)(ws);
        float* part = (float*)(ws + 52428800);
        float* u    = (float*)(ws + 52428800 + 18874368);
        float* wT   = (float*)(ws + 52428800 + 18874368 + 4718592);
        hipLaunchKernelGGL(wtrans_kernel, dim3((4 * 256 * 81 * 16 + 255) / 256), dim3(256), 0, stream, pw, wT);
        hipLaunchKernelGGL(conv1_kernel, dim3(4, 128), dim3(256), 0, stream, img, c1w, c1b, x);
        hipLaunchKernelGGL(pcaps_kernel, dim3(32, 4, 4), dim3(384), 0, stream, x, wT, part);
        hipLaunchKernelGGL(squash_kernel, dim3(576), dim3(256), 0, stream, part, pb, u, 4);
        hipLaunchKernelGGL(routing_kernel, dim3(128, 10), dim3(256), 0, stream, u, rw, out);
    }
}

// Round 9
// 408.881 us; speedup vs baseline: 2.0218x; 1.2151x over previous
//
#include <hip/hip_runtime.h>
#include <hip/hip_bf16.h>
#include <math.h>

// ---------------------------------------------------------------------------
// CapsuleNetwork forward.
// FAST PATH (ws >= 126,091,264 B): pcaps conv = fused-im2col split-bf16 MFMA.
//   conv1  : img -> x[128,256,20,20] fp32
//   xsplit : x -> xT hi/lo bf16, channel-last [128][400 pos][256 ic]
//   wsplit : pcaps_w -> Wf hi/lo [81 tap][16 icstep][256 oc][16 ic] frag order
//   gemm4  : 576 blocks = 72 mtiles(64 rows) x 8 tap groups (q=bid&7 ->
//            XCD-resident W chunk). A staged in LDS per tap via global_load_lds
//            (linear LDS dest, per-lane swizzled global src: cs = c ^ (r&7)).
//            8 waves = 2 mfrag x 4 ocgroup. 3-pass split bf16, reg dbuf frags.
//   squash(nq=8) -> u ; routing v2 (u_hat cached in LDS bf16) -> out
// FALLBACK: R5 fp32 direct-conv path.
// ---------------------------------------------------------------------------

typedef __attribute__((ext_vector_type(8)))  short  short8;
typedef __attribute__((ext_vector_type(8)))  ushort ushort8v;
typedef __attribute__((ext_vector_type(16))) float  f32x16;
#define MFMA32(a, b, c) __builtin_amdgcn_mfma_f32_32x32x16_bf16(a, b, c, 0, 0, 0)

__device__ __forceinline__ void split_bf16(float v, ushort& h, ushort& l) {
    __hip_bfloat16 hb = __float2bfloat16(v);
    float hf = __bfloat162float(hb);
    __hip_bfloat16 lb = __float2bfloat16(v - hf);
    h = *reinterpret_cast<ushort*>(&hb);
    l = *reinterpret_cast<ushort*>(&lb);
}

__device__ __forceinline__ void gl_lds16(const void* g, const void* lds_uniform_base) {
    __builtin_amdgcn_global_load_lds(
        (const __attribute__((address_space(1))) void*)g,
        (__attribute__((address_space(3))) void*)lds_uniform_base,
        16, 0, 0);
}

// ------------------------------- conv1 -------------------------------------
__global__ __launch_bounds__(256) void conv1_kernel(
    const float* __restrict__ img, const float* __restrict__ w,
    const float* __restrict__ bias, float* __restrict__ x)
{
    const int ct = blockIdx.x;
    const int b  = blockIdx.y;
    const int t  = threadIdx.x;
    __shared__ float img_s[784];
    __shared__ float w_s[64 * 81];
    for (int idx = t; idx < 784; idx += 256) img_s[idx] = img[b * 784 + idx];
    for (int idx = t; idx < 64 * 81; idx += 256) w_s[idx] = w[ct * 64 * 81 + idx];
    __syncthreads();
    for (int task = t; task < 1280; task += 256) {
        const int cl = task / 20;
        const int oy = task - cl * 20;
        float acc[20];
        const float bv = bias[ct * 64 + cl];
#pragma unroll
        for (int j = 0; j < 20; ++j) acc[j] = bv;
#pragma unroll
        for (int ky = 0; ky < 9; ++ky) {
            float rowv[28];
            const float* r = &img_s[(oy + ky) * 28];
#pragma unroll
            for (int j = 0; j < 28; ++j) rowv[j] = r[j];
#pragma unroll
            for (int kx = 0; kx < 9; ++kx) {
                const float wv = w_s[cl * 81 + ky * 9 + kx];
#pragma unroll
                for (int j = 0; j < 20; ++j) acc[j] += wv * rowv[j + kx];
            }
        }
        float* xp = x + (((size_t)b * 256 + ct * 64 + cl) * 400) + oy * 20;
#pragma unroll
        for (int j = 0; j < 20; ++j) xp[j] = fmaxf(acc[j], 0.f);
    }
}

// ----------------------------- xsplit (fast) --------------------------------
__global__ __launch_bounds__(256) void xsplit_kernel(
    const float* __restrict__ x, ushort* __restrict__ xTh, ushort* __restrict__ xTl)
{
    const int b   = blockIdx.x;   // 128
    const int icb = blockIdx.y;   // 8 (32 ic each)
    const int t   = threadIdx.x;
    __shared__ float xs[32 * 401];
    const float* xb = x + ((size_t)b * 256 + icb * 32) * 400;
    for (int idx = t; idx < 12800; idx += 256) {
        const int ic = idx / 400;
        const int p  = idx - ic * 400;
        xs[ic * 401 + p] = xb[idx];
    }
    __syncthreads();
    for (int u = t; u < 1600; u += 256) {
        const int c = u / 400;
        const int p = u - c * 400;
        ushort8v h8, l8;
#pragma unroll
        for (int j = 0; j < 8; ++j) {
            ushort hb, lb;
            split_bf16(xs[(c * 8 + j) * 401 + p], hb, lb);
            h8[j] = hb; l8[j] = lb;
        }
        const size_t o = ((size_t)b * 400 + p) * 256 + icb * 32 + c * 8;
        *(ushort8v*)(xTh + o) = h8;
        *(ushort8v*)(xTl + o) = l8;
    }
}

// ----------------------------- wsplit (fast) --------------------------------
__global__ __launch_bounds__(256) void wsplit_kernel(
    const float* __restrict__ pw, ushort* __restrict__ Wfh, ushort* __restrict__ Wfl)
{
    const int oc = blockIdx.x;    // 256
    const int t  = threadIdx.x;
    __shared__ float buf[1296];
    const float* row = pw + (size_t)oc * 20736;
    for (int s = 0; s < 16; ++s) {
        __syncthreads();
        for (int idx = t; idx < 1296; idx += 256) buf[idx] = row[s * 1296 + idx];
        __syncthreads();
        if (t < 81) {
            const int tap = t;
            ushort8v h0, l0, h1, l1;
#pragma unroll
            for (int j = 0; j < 8; ++j) {
                ushort hb, lb;
                split_bf16(buf[j * 81 + tap], hb, lb);
                h0[j] = hb; l0[j] = lb;
                split_bf16(buf[(8 + j) * 81 + tap], hb, lb);
                h1[j] = hb; l1[j] = lb;
            }
            const size_t rec = (((size_t)tap * 16 + s) * 256 + oc) * 16;
            *(ushort8v*)(Wfh + rec)     = h0;
            *(ushort8v*)(Wfh + rec + 8) = h1;
            *(ushort8v*)(Wfl + rec)     = l0;
            *(ushort8v*)(Wfl + rec + 8) = l1;
        }
    }
}

// ------------------------------ gemm4 (fast) --------------------------------
// 576 blocks: q = bid&7, mt = bid>>3 (64-row M tile). 512 thr = 8 waves:
// mf = w&1 (32-row m-frag), og = w>>1 (64-oc group). A staged in LDS per tap.
// LDS slot (p, mf, r, cs) holds xT(p)[row m=mt*64+mf*32+r][ic chunk c=cs^(r&7)].
__global__ __launch_bounds__(512, 4) void gemm4_kernel(
    const ushort* __restrict__ xTh, const ushort* __restrict__ xTl,
    const ushort* __restrict__ Wfh, const ushort* __restrict__ Wfl,
    float* __restrict__ part)
{
    const int bid = blockIdx.x;
    const int q = bid & 7, mt = bid >> 3;
    const int t = threadIdx.x;
    const int w = t >> 6, lane = t & 63;
    const int ln = lane & 31, h = lane >> 5, kh = h * 8;
    const int mf = w & 1, og = w >> 1;
    const int ts = (q * 81) >> 3, te = ((q + 1) * 81) >> 3;

    __shared__ ushort As[32768];   // 4096 slots x 16B = 64 KB: [p][mf][32 r][32 cs]

    // staging precompute: thread t stages 8 slots, j = i*512 + t (i 0..7);
    // p = i>>2, mfi = (i>>1)&1, r = ((i&1)<<4) + (t>>5), cs = t&31.
    uint goff[4];
    {
        const int cs = t & 31;
        const int rlo = t >> 5;
#pragma unroll
        for (int k = 0; k < 4; ++k) {
            const int mfi = k >> 1;
            const int r   = ((k & 1) << 4) + rlo;
            const int m   = mt * 64 + mfi * 32 + r;
            const int b   = m / 36, pos = m - b * 36;
            const int oy  = pos / 6, ox = pos - oy * 6;
            const int c   = cs ^ (r & 7);
            goff[k] = ((uint)(b * 400 + oy * 40 + ox * 2) << 9) + ((uint)c << 4);
        }
    }

#define GEMM4_STAGE(tap_)                                                      \
    {                                                                          \
        const int ky_ = (tap_) / 9, kx_ = (tap_) - 9 * ky_;                    \
        const uint toff = (uint)((ky_ * 20 + kx_) << 9);                       \
        _Pragma("unroll")                                                      \
        for (int i = 0; i < 4; ++i) {                                          \
            gl_lds16((const char*)xTh + goff[i] + toff,                        \
                     (char*)As + (i * 512 + w * 64) * 16);                     \
            gl_lds16((const char*)xTl + goff[i] + toff,                        \
                     (char*)As + 32768 + (i * 512 + w * 64) * 16);             \
        }                                                                      \
    }

    f32x16 acc0, acc1;
#pragma unroll
    for (int i = 0; i < 16; ++i) { acc0[i] = 0.f; acc1[i] = 0.f; }

    // compute-lane LDS addressing (ushort indices)
    const int rx7   = ln & 7;
    const uint abase = (uint)(mf * 1024 + ln * 32) * 8;   // slot*8 ushorts

    GEMM4_STAGE(ts);
    __syncthreads();

    for (int tap = ts; tap < te; ++tap) {
        const ushort* wr_h = Wfh + (((size_t)tap * 16) * 256 + og * 64 + ln) * 16 + kh;
        const ushort* wr_l = Wfl + (((size_t)tap * 16) * 256 + og * 64 + ln) * 16 + kh;
        // s = 0 fragments
        int cs0 = (0 + h) ^ rx7;
        short8 cah  = *(const short8*)(As + abase + cs0 * 8);
        short8 cal  = *(const short8*)(As + 16384 + abase + cs0 * 8);
        short8 cw0h = *(const short8*)(wr_h);
        short8 cw1h = *(const short8*)(wr_h + 512);
        short8 cw0l = *(const short8*)(wr_l);
        short8 cw1l = *(const short8*)(wr_l + 512);
#pragma unroll
        for (int s = 0; s < 16; ++s) {
            const int wstep = (s < 15) ? 4096 : 0;
            const int sp = (s < 15) ? s + 1 : 15;
            const int csn = (2 * sp + h) ^ rx7;
            const short8 nah  = *(const short8*)(As + abase + csn * 8);
            const short8 nal  = *(const short8*)(As + 16384 + abase + csn * 8);
            const short8 nw0h = *(const short8*)(wr_h + wstep);
            const short8 nw1h = *(const short8*)(wr_h + wstep + 512);
            const short8 nw0l = *(const short8*)(wr_l + wstep);
            const short8 nw1l = *(const short8*)(wr_l + wstep + 512);
            acc0 = MFMA32(cah, cw0h, acc0);
            acc0 = MFMA32(cal, cw0h, acc0);
            acc0 = MFMA32(cah, cw0l, acc0);
            acc1 = MFMA32(cah, cw1h, acc1);
            acc1 = MFMA32(cal, cw1h, acc1);
            acc1 = MFMA32(cah, cw1l, acc1);
            cah = nah; cal = nal;
            cw0h = nw0h; cw1h = nw1h; cw0l = nw0l; cw1l = nw1l;
            wr_h += wstep; wr_l += wstep;
        }
        if (tap + 1 < te) {
            __syncthreads();            // all waves done reading As for this tap
            GEMM4_STAGE(tap + 1);
            __syncthreads();            // staging drained (implicit vmcnt(0))
        }
    }
#undef GEMM4_STAGE

    // epilogue: C[m][oc] -> part[q][b][cap][pos][d]
    float* pq = part + (size_t)q * 1179648;
#pragma unroll
    for (int nf = 0; nf < 2; ++nf) {
        const f32x16 a = nf ? acc1 : acc0;
        const int oc = og * 64 + nf * 32 + ln;
        float* pb = pq + (oc >> 3) * 288 + (oc & 7);
#pragma unroll
        for (int r = 0; r < 16; ++r) {
            const int m = mt * 64 + mf * 32 + (r & 3) + 8 * (r >> 2) + 4 * h;
            const int b = m / 36;
            const int pos = m - b * 36;
            pb[(size_t)b * 9216 + pos * 8] = a[r];
        }
    }
}

// ------------------------------- squash ------------------------------------
__global__ __launch_bounds__(256) void squash_kernel(
    const float* __restrict__ part, const float* __restrict__ bias,
    float* __restrict__ u, int nq)
{
    const int idx = blockIdx.x * 256 + threadIdx.x;
    if (idx >= 128 * 1152) return;
    const int i   = idx % 1152;
    const int cap = i / 36;
    float v[8];
    float n2 = 0.f;
#pragma unroll
    for (int c = 0; c < 8; ++c) {
        float s = bias[cap * 8 + c];
        for (int qq = 0; qq < nq; ++qq) s += part[(size_t)qq * 1179648 + (size_t)idx * 8 + c];
        v[c] = s;
        n2 += s * s;
    }
    const float sc = sqrtf(n2) / (1.f + n2);
#pragma unroll
    for (int c = 0; c < 8; ++c) u[(size_t)idx * 8 + c] = v[c] * sc;
}

// ------------------------------- routing v2 --------------------------------
__device__ __forceinline__ float4 uhat4(const float* __restrict__ urow,
                                        const float* __restrict__ wrow)
{
    float ur[8];
    const float4 u0 = *(const float4*)urow;
    const float4 u1 = *(const float4*)(urow + 4);
    ur[0] = u0.x; ur[1] = u0.y; ur[2] = u0.z; ur[3] = u0.w;
    ur[4] = u1.x; ur[5] = u1.y; ur[6] = u1.z; ur[7] = u1.w;
    float4 uh = make_float4(0.f, 0.f, 0.f, 0.f);
#pragma unroll
    for (int c = 0; c < 8; ++c) {
        const float4 wv = *(const float4*)(wrow + c * 16);
        uh.x += ur[c] * wv.x; uh.y += ur[c] * wv.y;
        uh.z += ur[c] * wv.z; uh.w += ur[c] * wv.w;
    }
    return uh;
}

__device__ __forceinline__ float4 uh_from_lds(const ushort* uhs, int i, int d4)
{
    const uint2 rv = *(const uint2*)(uhs + i * 16 + d4);
    float4 r;
    r.x = __uint_as_float((rv.x & 0xffffu) << 16);
    r.y = __uint_as_float((rv.x >> 16) << 16);
    r.z = __uint_as_float((rv.y & 0xffffu) << 16);
    r.w = __uint_as_float((rv.y >> 16) << 16);
    return r;
}

__global__ __launch_bounds__(256) void routing_kernel(
    const float* __restrict__ u, const float* __restrict__ rw,
    float* __restrict__ out)
{
    const int b = blockIdx.x;
    const int o = blockIdx.y;
    const int t = threadIdx.x;
    __shared__ ushort uh_s[1152 * 16];
    __shared__ float logits[1152];
    __shared__ float ebuf[1152];
    __shared__ float psum[64][17];
    __shared__ float red[8];
    __shared__ float v_s[16];
    const float* ub = u + (size_t)b * 9216;
    const float* wo = rw + (size_t)o * 147456;
    for (int i = t; i < 1152; i += 256) logits[i] = 0.f;
    __syncthreads();
    const int dq = t & 3;
    const int ig = t >> 2;
    const int d4 = dq * 4;
    for (int iter = 1; iter <= 3; ++iter) {
        float lmax = -3.0e38f;
        for (int i = t; i < 1152; i += 256) lmax = fmaxf(lmax, logits[i]);
#pragma unroll
        for (int off = 32; off; off >>= 1) lmax = fmaxf(lmax, __shfl_xor(lmax, off, 64));
        if ((t & 63) == 0) red[t >> 6] = lmax;
        __syncthreads();
        const float m = fmaxf(fmaxf(red[0], red[1]), fmaxf(red[2], red[3]));
        float ls = 0.f;
        for (int i = t; i < 1152; i += 256) {
            const float e = expf(logits[i] - m);
            ebuf[i] = e;
            ls += e;
        }
#pragma unroll
        for (int off = 32; off; off >>= 1) ls += __shfl_xor(ls, off, 64);
        if ((t & 63) == 0) red[4 + (t >> 6)] = ls;
        __syncthreads();
        const float sumE = red[4] + red[5] + red[6] + red[7];
        float4 ps = make_float4(0.f, 0.f, 0.f, 0.f);
        if (iter == 1) {
            for (int i = ig; i < 1152; i += 64) {
                const float4 uh = uhat4(ub + i * 8, wo + (size_t)i * 128 + d4);
                ushort4 hb;
                __hip_bfloat16 q0 = __float2bfloat16(uh.x);
                __hip_bfloat16 q1 = __float2bfloat16(uh.y);
                __hip_bfloat16 q2 = __float2bfloat16(uh.z);
                __hip_bfloat16 q3 = __float2bfloat16(uh.w);
                hb.x = *(ushort*)&q0; hb.y = *(ushort*)&q1;
                hb.z = *(ushort*)&q2; hb.w = *(ushort*)&q3;
                *(ushort4*)(uh_s + i * 16 + d4) = hb;
                const float e = ebuf[i];
                ps.x += e * uh.x; ps.y += e * uh.y; ps.z += e * uh.z; ps.w += e * uh.w;
            }
        } else {
            for (int i = ig; i < 1152; i += 64) {
                const float4 uh = uh_from_lds(uh_s, i, d4);
                const float e = ebuf[i];
                ps.x += e * uh.x; ps.y += e * uh.y; ps.z += e * uh.z; ps.w += e * uh.w;
            }
        }
        psum[ig][d4 + 0] = ps.x; psum[ig][d4 + 1] = ps.y;
        psum[ig][d4 + 2] = ps.z; psum[ig][d4 + 3] = ps.w;
        __syncthreads();
        if (t < 16) {
            float s = 0.f;
            for (int g = 0; g < 64; ++g) s += psum[g][t];
            s /= sumE;
            float qn = s * s;
            qn += __shfl_xor(qn, 1, 16); qn += __shfl_xor(qn, 2, 16);
            qn += __shfl_xor(qn, 4, 16); qn += __shfl_xor(qn, 8, 16);
            v_s[t] = s * sqrtf(qn) / (1.f + qn);
        }
        __syncthreads();
        if (iter < 3) {
            const float v0 = v_s[d4 + 0], v1 = v_s[d4 + 1];
            const float v2 = v_s[d4 + 2], v3 = v_s[d4 + 3];
            for (int i = ig; i < 1152; i += 64) {
                const float4 uh = uh_from_lds(uh_s, i, d4);
                float pr = uh.x * v0 + uh.y * v1 + uh.z * v2 + uh.w * v3;
                pr += __shfl_xor(pr, 1, 64);
                pr += __shfl_xor(pr, 2, 64);
                if (dq == 0) logits[i] += pr;
            }
            __syncthreads();
        }
    }
    if (t < 16) out[((size_t)b * 10 + o) * 16 + t] = v_s[t];
}

// ===================== FALLBACK (R5 fp32 direct conv) ======================
#define WSL4 1344

__global__ __launch_bounds__(256) void wtrans_kernel(
    const float* __restrict__ w, float* __restrict__ wT)
{
    const int idx = blockIdx.x * 256 + threadIdx.x;
    if (idx >= 4 * 256 * 81 * 16) return;
    const int c      = idx & 15;
    const int k      = (idx >> 4) % 81;
    const int ic     = ((idx >> 4) / 81) % 256;
    const int octile = idx / (16 * 81 * 256);
    const int ocb    = octile * 64 + c * 4;
    float4 v;
    v.x = w[((size_t)(ocb + 0) * 256 + ic) * 81 + k];
    v.y = w[((size_t)(ocb + 1) * 256 + ic) * 81 + k];
    v.z = w[((size_t)(ocb + 2) * 256 + ic) * 81 + k];
    v.w = w[((size_t)(ocb + 3) * 256 + ic) * 81 + k];
    ((float4*)wT)[((size_t)octile * 256 + ic) * WSL4 + k * 16 + c] = v;
}

__global__ __launch_bounds__(384) void pcaps_kernel(
    const float* __restrict__ x, const float* __restrict__ wT,
    float* __restrict__ part)
{
    const int btile  = blockIdx.x;
    const int octile = blockIdx.y;
    const int ict    = blockIdx.z;
    const int t    = threadIdx.x;
    const int wave = t >> 6;
    const int lane = t & 63;
    __shared__ float4 w_s[2][WSL4];
    __shared__ float4 x_s[2][448];
    const int oc4  = (t & 15) * 4;
    const int slot = t >> 4;
    const int bb   = slot / 6;
    const int oy   = slot - 6 * bb;
    const int b0   = btile * 4;
    float acc[6][4];
#pragma unroll
    for (int p = 0; p < 6; ++p) {
        acc[p][0] = 0.f; acc[p][1] = 0.f; acc[p][2] = 0.f; acc[p][3] = 0.f;
    }
    const float*  xg   = x + (size_t)b0 * 102400 + (size_t)ict * 25600;
    const float4* wsrc = (const float4*)wT + ((size_t)octile * 256 + ict * 64) * WSL4;
#define PCAPS_STAGE(bf_, ic_)                                                  \
    {                                                                          \
        const float4* gsl = wsrc + (size_t)(ic_) * WSL4;                       \
        for (int ch = wave; ch < 21; ch += 6)                                  \
            gl_lds16(gsl + ch * 64 + lane, &w_s[bf_][ch * 64]);                \
        for (int ch = wave; ch < 7; ch += 6) {                                 \
            int idx = ch * 64 + lane;                                          \
            if (idx >= 400) idx = 0;                                           \
            const int xbb = idx / 100;                                         \
            const int off = idx - xbb * 100;                                   \
            const float* g = xg + (size_t)xbb * 102400 + (ic_) * 400 + off * 4;\
            gl_lds16(g, &x_s[bf_][ch * 64]);                                   \
        }                                                                      \
    }
    PCAPS_STAGE(0, 0);
    __syncthreads();
    int buf = 0;
    for (int ic = 0; ic < 64; ++ic) {
        if (ic < 63) PCAPS_STAGE(buf ^ 1, ic + 1);
        const float* xrow = (const float*)x_s[buf] + bb * 400;
        const float* wrow = (const float*)w_s[buf];
#pragma unroll
        for (int ky = 0; ky < 9; ++ky) {
            float rowv[20];
            const float4* xr = (const float4*)&xrow[(2 * oy + ky) * 20];
#pragma unroll
            for (int j = 0; j < 5; ++j) ((float4*)rowv)[j] = xr[j];
#pragma unroll
            for (int kx = 0; kx < 9; ++kx) {
                const float4 wv = *(const float4*)&wrow[(ky * 9 + kx) * 64 + oc4];
#pragma unroll
                for (int p = 0; p < 6; ++p) {
                    const float xv = rowv[2 * p + kx];
                    acc[p][0] += xv * wv.x; acc[p][1] += xv * wv.y;
                    acc[p][2] += xv * wv.z; acc[p][3] += xv * wv.w;
                }
            }
        }
        __syncthreads();
        buf ^= 1;
    }
#undef PCAPS_STAGE
    float* pb = part + ((size_t)ict * 128 + (b0 + bb)) * 9216;
    const int oc0 = octile * 64 + oc4;
    const int cap = oc0 >> 3;
    const int d0  = oc0 & 7;
#pragma unroll
    for (int p = 0; p < 6; ++p) {
        const int pos = oy * 6 + p;
        *(float4*)&pb[((size_t)cap * 36 + pos) * 8 + d0] =
            make_float4(acc[p][0], acc[p][1], acc[p][2], acc[p][3]);
    }
}

// ------------------------------- launcher ----------------------------------
extern "C" void kernel_launch(void* const* d_in, const int* in_sizes, int n_in,
                              void* d_out, int out_size, void* d_ws, size_t ws_size,
                              hipStream_t stream)
{
    const float* img = (const float*)d_in[0];
    const float* c1w = (const float*)d_in[1];
    const float* c1b = (const float*)d_in[2];
    const float* pw  = (const float*)d_in[3];
    const float* pb  = (const float*)d_in[4];
    const float* rw  = (const float*)d_in[5];
    float* out = (float*)d_out;
    char* ws = (char*)d_ws;

    if (ws_size >= 126091264ULL) {
        // fast path: fused-im2col split-bf16 MFMA GEMM (126.09 MB)
        float*  x    = (float*)(ws);                  // 52,428,800 B (dead after xsplit)
        float*  part = (float*)(ws);                  // 37,748,736 B (aliases x)
        float*  u    = (float*)(ws + 37748736);       //  4,718,592 B (aliases x)
        ushort* xTh  = (ushort*)(ws + 52428800);      // 26,214,400 B
        ushort* xTl  = (ushort*)(ws + 78643200);      // 26,214,400 B
        ushort* Wfh  = (ushort*)(ws + 104857600);     // 10,616,832 B
        ushort* Wfl  = (ushort*)(ws + 115474432);     // 10,616,832 B
        hipLaunchKernelGGL(conv1_kernel, dim3(4, 128), dim3(256), 0, stream, img, c1w, c1b, x);
        hipLaunchKernelGGL(xsplit_kernel, dim3(128, 8), dim3(256), 0, stream, x, xTh, xTl);
        hipLaunchKernelGGL(wsplit_kernel, dim3(256), dim3(256), 0, stream, pw, Wfh, Wfl);
        hipLaunchKernelGGL(gemm4_kernel, dim3(576), dim3(512), 0, stream, xTh, xTl, Wfh, Wfl, part);
        hipLaunchKernelGGL(squash_kernel, dim3(576), dim3(256), 0, stream, part, pb, u, 8);
        hipLaunchKernelGGL(routing_kernel, dim3(128, 10), dim3(256), 0, stream, u, rw, out);
    } else {
        // fallback: R5 fp32 direct conv (97.9 MB, proven)
        float* x    = (float*)(ws);
        float* part = (float*)(ws + 52428800);
        float* u    = (float*)(ws + 52428800 + 18874368);
        float* wT   = (float*)(ws + 52428800 + 18874368 + 4718592);
        hipLaunchKernelGGL(wtrans_kernel, dim3((4 * 256 * 81 * 16 + 255) / 256), dim3(256), 0, stream, pw, wT);
        hipLaunchKernelGGL(conv1_kernel, dim3(4, 128), dim3(256), 0, stream, img, c1w, c1b, x);
        hipLaunchKernelGGL(pcaps_kernel, dim3(32, 4, 4), dim3(384), 0, stream, x, wT, part);
        hipLaunchKernelGGL(squash_kernel, dim3(576), dim3(256), 0, stream, part, pb, u, 4);
        hipLaunchKernelGGL(routing_kernel, dim3(128, 10), dim3(256), 0, stream, u, rw, out);
    }
}

// Round 10
// 370.188 us; speedup vs baseline: 2.2332x; 1.1045x over previous
//
#include <hip/hip_runtime.h>
#include <hip/hip_bf16.h>
#include <math.h>

// ---------------------------------------------------------------------------
// CapsuleNetwork forward.
// FAST PATH (ws >= 126,091,264 B): pcaps conv = fused-im2col split-bf16 MFMA.
//   conv1  : img -> x[128,256,20,20] fp32
//   xsplit : x -> xT hi/lo bf16, channel-last [128][400 pos][256 ic]
//   wsplit : pcaps_w -> Wf hi/lo [81 tap][16 icstep][256 oc][16 ic] frag order
//   gemm5  : 576 blocks = 72 mtiles(64 rows) x 8 tap groups (q=bid&7).
//            8 waves = 4 ocgroups x 2 K-halves; each wave = 2 mfrag x 2 nfrag
//            (12 MFMA per 4 A-ds + 4 W-global loads -> W traffic halved vs R9).
//            A staged in LDS per tap via global_load_lds (linear dest,
//            swizzled source cs = c ^ (r&7)). Cross-kh reduce via LDS epilogue.
//   squash(nq=8) -> u ; routing v2 (u_hat cached in LDS bf16) -> out
// FALLBACK: R5 fp32 direct-conv path.
// ---------------------------------------------------------------------------

typedef __attribute__((ext_vector_type(8)))  short  short8;
typedef __attribute__((ext_vector_type(8)))  ushort ushort8v;
typedef __attribute__((ext_vector_type(16))) float  f32x16;
#define MFMA32(a, b, c) __builtin_amdgcn_mfma_f32_32x32x16_bf16(a, b, c, 0, 0, 0)

__device__ __forceinline__ void split_bf16(float v, ushort& h, ushort& l) {
    __hip_bfloat16 hb = __float2bfloat16(v);
    float hf = __bfloat162float(hb);
    __hip_bfloat16 lb = __float2bfloat16(v - hf);
    h = *reinterpret_cast<ushort*>(&hb);
    l = *reinterpret_cast<ushort*>(&lb);
}

__device__ __forceinline__ void gl_lds16(const void* g, const void* lds_uniform_base) {
    __builtin_amdgcn_global_load_lds(
        (const __attribute__((address_space(1))) void*)g,
        (__attribute__((address_space(3))) void*)lds_uniform_base,
        16, 0, 0);
}

// ------------------------------- conv1 -------------------------------------
__global__ __launch_bounds__(256) void conv1_kernel(
    const float* __restrict__ img, const float* __restrict__ w,
    const float* __restrict__ bias, float* __restrict__ x)
{
    const int ct = blockIdx.x;
    const int b  = blockIdx.y;
    const int t  = threadIdx.x;
    __shared__ float img_s[784];
    __shared__ float w_s[64 * 81];
    for (int idx = t; idx < 784; idx += 256) img_s[idx] = img[b * 784 + idx];
    for (int idx = t; idx < 64 * 81; idx += 256) w_s[idx] = w[ct * 64 * 81 + idx];
    __syncthreads();
    for (int task = t; task < 1280; task += 256) {
        const int cl = task / 20;
        const int oy = task - cl * 20;
        float acc[20];
        const float bv = bias[ct * 64 + cl];
#pragma unroll
        for (int j = 0; j < 20; ++j) acc[j] = bv;
#pragma unroll
        for (int ky = 0; ky < 9; ++ky) {
            float rowv[28];
            const float* r = &img_s[(oy + ky) * 28];
#pragma unroll
            for (int j = 0; j < 28; ++j) rowv[j] = r[j];
#pragma unroll
            for (int kx = 0; kx < 9; ++kx) {
                const float wv = w_s[cl * 81 + ky * 9 + kx];
#pragma unroll
                for (int j = 0; j < 20; ++j) acc[j] += wv * rowv[j + kx];
            }
        }
        float* xp = x + (((size_t)b * 256 + ct * 64 + cl) * 400) + oy * 20;
#pragma unroll
        for (int j = 0; j < 20; ++j) xp[j] = fmaxf(acc[j], 0.f);
    }
}

// ----------------------------- xsplit (fast) --------------------------------
__global__ __launch_bounds__(256) void xsplit_kernel(
    const float* __restrict__ x, ushort* __restrict__ xTh, ushort* __restrict__ xTl)
{
    const int b   = blockIdx.x;   // 128
    const int icb = blockIdx.y;   // 8 (32 ic each)
    const int t   = threadIdx.x;
    __shared__ float xs[32 * 401];
    const float* xb = x + ((size_t)b * 256 + icb * 32) * 400;
    for (int idx = t; idx < 12800; idx += 256) {
        const int ic = idx / 400;
        const int p  = idx - ic * 400;
        xs[ic * 401 + p] = xb[idx];
    }
    __syncthreads();
    for (int u = t; u < 1600; u += 256) {
        const int c = u / 400;
        const int p = u - c * 400;
        ushort8v h8, l8;
#pragma unroll
        for (int j = 0; j < 8; ++j) {
            ushort hb, lb;
            split_bf16(xs[(c * 8 + j) * 401 + p], hb, lb);
            h8[j] = hb; l8[j] = lb;
        }
        const size_t o = ((size_t)b * 400 + p) * 256 + icb * 32 + c * 8;
        *(ushort8v*)(xTh + o) = h8;
        *(ushort8v*)(xTl + o) = l8;
    }
}

// ----------------------------- wsplit (fast) --------------------------------
__global__ __launch_bounds__(256) void wsplit_kernel(
    const float* __restrict__ pw, ushort* __restrict__ Wfh, ushort* __restrict__ Wfl)
{
    const int oc = blockIdx.x;    // 256
    const int t  = threadIdx.x;
    __shared__ float buf[1296];
    const float* row = pw + (size_t)oc * 20736;
    for (int s = 0; s < 16; ++s) {
        __syncthreads();
        for (int idx = t; idx < 1296; idx += 256) buf[idx] = row[s * 1296 + idx];
        __syncthreads();
        if (t < 81) {
            const int tap = t;
            ushort8v h0, l0, h1, l1;
#pragma unroll
            for (int j = 0; j < 8; ++j) {
                ushort hb, lb;
                split_bf16(buf[j * 81 + tap], hb, lb);
                h0[j] = hb; l0[j] = lb;
                split_bf16(buf[(8 + j) * 81 + tap], hb, lb);
                h1[j] = hb; l1[j] = lb;
            }
            const size_t rec = (((size_t)tap * 16 + s) * 256 + oc) * 16;
            *(ushort8v*)(Wfh + rec)     = h0;
            *(ushort8v*)(Wfh + rec + 8) = h1;
            *(ushort8v*)(Wfl + rec)     = l0;
            *(ushort8v*)(Wfl + rec + 8) = l1;
        }
    }
}

// ------------------------------ gemm5 (fast) --------------------------------
// 576 blocks: q = bid&7, mt = bid>>3 (64-row M tile). 512 thr = 8 waves:
// og = w&3 (64-oc group), kh = w>>2 (icstep half). Wave computes 2 mfrag x
// 2 nfrag over its 8 icsteps per tap. Cross-kh reduce via LDS at the end.
__global__ __launch_bounds__(512, 4) void gemm5_kernel(
    const ushort* __restrict__ xTh, const ushort* __restrict__ xTl,
    const ushort* __restrict__ Wfh, const ushort* __restrict__ Wfl,
    float* __restrict__ part)
{
    const int bid = blockIdx.x;
    const int q = bid & 7, mt = bid >> 3;
    const int t = threadIdx.x;
    const int w = t >> 6, lane = t & 63;
    const int ln = lane & 31, h = lane >> 5, kh8 = h * 8;
    const int og = w & 3, kh = w >> 2;
    const int ts = (q * 81) >> 3, te = ((q + 1) * 81) >> 3;

    __shared__ ushort As[32768];   // 64 KB: hi slots 0..2047, lo 2048..4095

    // staging precompute (slot j = i*512 + t; r = ((i&1)<<4)+(t>>5), cs = t&31)
    uint goff[4];
    {
        const int cs = t & 31;
        const int rlo = t >> 5;
#pragma unroll
        for (int k = 0; k < 4; ++k) {
            const int mfi = k >> 1;
            const int r   = ((k & 1) << 4) + rlo;
            const int m   = mt * 64 + mfi * 32 + r;
            const int b   = m / 36, pos = m - b * 36;
            const int oy  = pos / 6, ox = pos - oy * 6;
            const int c   = cs ^ (r & 7);
            goff[k] = ((uint)(b * 400 + oy * 40 + ox * 2) << 9) + ((uint)c << 4);
        }
    }

#define GEMM5_STAGE(tap_)                                                      \
    {                                                                          \
        const int ky_ = (tap_) / 9, kx_ = (tap_) - 9 * ky_;                    \
        const uint toff = (uint)((ky_ * 20 + kx_) << 9);                       \
        _Pragma("unroll")                                                      \
        for (int i = 0; i < 4; ++i) {                                          \
            gl_lds16((const char*)xTh + goff[i] + toff,                        \
                     (char*)As + (i * 512 + w * 64) * 16);                     \
            gl_lds16((const char*)xTl + goff[i] + toff,                        \
                     (char*)As + 32768 + (i * 512 + w * 64) * 16);             \
        }                                                                      \
    }

    f32x16 acc00, acc01, acc10, acc11;   // [mfrag][nfrag]
#pragma unroll
    for (int i = 0; i < 16; ++i) { acc00[i] = 0.f; acc01[i] = 0.f; acc10[i] = 0.f; acc11[i] = 0.f; }

    const int rx7 = ln & 7;
    const uint ab0 = (uint)(ln * 32) * 8;          // mf=0 slot base (ushort idx)
    const uint ab1 = (uint)(1024 + ln * 32) * 8;   // mf=1

    GEMM5_STAGE(ts);
    __syncthreads();

    for (int tap = ts; tap < te; ++tap) {
        const size_t wbase = (((size_t)tap * 16 + kh * 8) * 256 + og * 64 + ln) * 16 + kh8;
        const ushort* wr_h = Wfh + wbase;
        const ushort* wr_l = Wfl + wbase;
        short8 cw0h = *(const short8*)(wr_h);
        short8 cw1h = *(const short8*)(wr_h + 512);
        short8 cw0l = *(const short8*)(wr_l);
        short8 cw1l = *(const short8*)(wr_l + 512);
#pragma unroll
        for (int j = 0; j < 8; ++j) {
            const int s = kh * 8 + j;
            const int cs = (2 * s + h) ^ rx7;
            const short8 a0h = *(const short8*)(As + ab0 + cs * 8);
            const short8 a0l = *(const short8*)(As + 16384 + ab0 + cs * 8);
            const short8 a1h = *(const short8*)(As + ab1 + cs * 8);
            const short8 a1l = *(const short8*)(As + 16384 + ab1 + cs * 8);
            const int wstep = (j < 7) ? 4096 : 0;   // W prefetch (branchless)
            const short8 nw0h = *(const short8*)(wr_h + wstep);
            const short8 nw1h = *(const short8*)(wr_h + wstep + 512);
            const short8 nw0l = *(const short8*)(wr_l + wstep);
            const short8 nw1l = *(const short8*)(wr_l + wstep + 512);
            acc00 = MFMA32(a0h, cw0h, acc00);
            acc00 = MFMA32(a0l, cw0h, acc00);
            acc00 = MFMA32(a0h, cw0l, acc00);
            acc01 = MFMA32(a0h, cw1h, acc01);
            acc01 = MFMA32(a0l, cw1h, acc01);
            acc01 = MFMA32(a0h, cw1l, acc01);
            acc10 = MFMA32(a1h, cw0h, acc10);
            acc10 = MFMA32(a1l, cw0h, acc10);
            acc10 = MFMA32(a1h, cw0l, acc10);
            acc11 = MFMA32(a1h, cw1h, acc11);
            acc11 = MFMA32(a1l, cw1h, acc11);
            acc11 = MFMA32(a1h, cw1l, acc11);
            cw0h = nw0h; cw1h = nw1h; cw0l = nw0l; cw1l = nw1l;
            wr_h += wstep; wr_l += wstep;
        }
        if (tap + 1 < te) {
            __syncthreads();            // all waves done reading As
            GEMM5_STAGE(tap + 1);
            __syncthreads();            // staging drained (implicit vmcnt(0))
        }
    }
#undef GEMM5_STAGE

    // ---- cross-kh reduction through As (64 KB = 4096 float4) ----
    __syncthreads();                    // everyone done with As as A-tile
    float4* red4 = (float4*)As;
    const int cidx = og * 64 + lane;    // 0..255
    if (kh == 1) {
#pragma unroll
        for (int e4 = 0; e4 < 16; ++e4) {
            const int g = e4 >> 2, i0 = (e4 & 3) * 4;
            const f32x16 a = (g == 0) ? acc00 : (g == 1) ? acc01 : (g == 2) ? acc10 : acc11;
            red4[e4 * 256 + cidx] = make_float4(a[i0], a[i0 + 1], a[i0 + 2], a[i0 + 3]);
        }
    }
    __syncthreads();
    if (kh == 0) {
#pragma unroll
        for (int e4 = 0; e4 < 16; ++e4) {
            const int g = e4 >> 2, i0 = (e4 & 3) * 4;
            const float4 v = red4[e4 * 256 + cidx];
            if (g == 0) { acc00[i0] += v.x; acc00[i0+1] += v.y; acc00[i0+2] += v.z; acc00[i0+3] += v.w; }
            if (g == 1) { acc01[i0] += v.x; acc01[i0+1] += v.y; acc01[i0+2] += v.z; acc01[i0+3] += v.w; }
            if (g == 2) { acc10[i0] += v.x; acc10[i0+1] += v.y; acc10[i0+2] += v.z; acc10[i0+3] += v.w; }
            if (g == 3) { acc11[i0] += v.x; acc11[i0+1] += v.y; acc11[i0+2] += v.z; acc11[i0+3] += v.w; }
        }
        // epilogue: C[m][oc] -> part[q][b][cap][pos][d]
        float* pq = part + (size_t)q * 1179648;
#pragma unroll
        for (int mf = 0; mf < 2; ++mf) {
#pragma unroll
            for (int nf = 0; nf < 2; ++nf) {
                const f32x16 a = (mf == 0) ? (nf == 0 ? acc00 : acc01)
                                           : (nf == 0 ? acc10 : acc11);
                const int oc = og * 64 + nf * 32 + ln;
                float* pb = pq + (oc >> 3) * 288 + (oc & 7);
#pragma unroll
                for (int r = 0; r < 16; ++r) {
                    const int m = mt * 64 + mf * 32 + (r & 3) + 8 * (r >> 2) + 4 * h;
                    const int b = m / 36;
                    const int pos = m - b * 36;
                    pb[(size_t)b * 9216 + pos * 8] = a[r];
                }
            }
        }
    }
}

// ------------------------------- squash ------------------------------------
__global__ __launch_bounds__(256) void squash_kernel(
    const float* __restrict__ part, const float* __restrict__ bias,
    float* __restrict__ u, int nq)
{
    const int idx = blockIdx.x * 256 + threadIdx.x;
    if (idx >= 128 * 1152) return;
    const int i   = idx % 1152;
    const int cap = i / 36;
    float v[8];
    float n2 = 0.f;
#pragma unroll
    for (int c = 0; c < 8; ++c) {
        float s = bias[cap * 8 + c];
        for (int qq = 0; qq < nq; ++qq) s += part[(size_t)qq * 1179648 + (size_t)idx * 8 + c];
        v[c] = s;
        n2 += s * s;
    }
    const float sc = sqrtf(n2) / (1.f + n2);
#pragma unroll
    for (int c = 0; c < 8; ++c) u[(size_t)idx * 8 + c] = v[c] * sc;
}

// ------------------------------- routing v2 --------------------------------
__device__ __forceinline__ float4 uhat4(const float* __restrict__ urow,
                                        const float* __restrict__ wrow)
{
    float ur[8];
    const float4 u0 = *(const float4*)urow;
    const float4 u1 = *(const float4*)(urow + 4);
    ur[0] = u0.x; ur[1] = u0.y; ur[2] = u0.z; ur[3] = u0.w;
    ur[4] = u1.x; ur[5] = u1.y; ur[6] = u1.z; ur[7] = u1.w;
    float4 uh = make_float4(0.f, 0.f, 0.f, 0.f);
#pragma unroll
    for (int c = 0; c < 8; ++c) {
        const float4 wv = *(const float4*)(wrow + c * 16);
        uh.x += ur[c] * wv.x; uh.y += ur[c] * wv.y;
        uh.z += ur[c] * wv.z; uh.w += ur[c] * wv.w;
    }
    return uh;
}

__device__ __forceinline__ float4 uh_from_lds(const ushort* uhs, int i, int d4)
{
    const uint2 rv = *(const uint2*)(uhs + i * 16 + d4);
    float4 r;
    r.x = __uint_as_float((rv.x & 0xffffu) << 16);
    r.y = __uint_as_float((rv.x >> 16) << 16);
    r.z = __uint_as_float((rv.y & 0xffffu) << 16);
    r.w = __uint_as_float((rv.y >> 16) << 16);
    return r;
}

__global__ __launch_bounds__(256) void routing_kernel(
    const float* __restrict__ u, const float* __restrict__ rw,
    float* __restrict__ out)
{
    const int b = blockIdx.x;
    const int o = blockIdx.y;
    const int t = threadIdx.x;
    __shared__ ushort uh_s[1152 * 16];
    __shared__ float logits[1152];
    __shared__ float ebuf[1152];
    __shared__ float psum[64][17];
    __shared__ float red[8];
    __shared__ float v_s[16];
    const float* ub = u + (size_t)b * 9216;
    const float* wo = rw + (size_t)o * 147456;
    for (int i = t; i < 1152; i += 256) logits[i] = 0.f;
    __syncthreads();
    const int dq = t & 3;
    const int ig = t >> 2;
    const int d4 = dq * 4;
    for (int iter = 1; iter <= 3; ++iter) {
        float lmax = -3.0e38f;
        for (int i = t; i < 1152; i += 256) lmax = fmaxf(lmax, logits[i]);
#pragma unroll
        for (int off = 32; off; off >>= 1) lmax = fmaxf(lmax, __shfl_xor(lmax, off, 64));
        if ((t & 63) == 0) red[t >> 6] = lmax;
        __syncthreads();
        const float m = fmaxf(fmaxf(red[0], red[1]), fmaxf(red[2], red[3]));
        float ls = 0.f;
        for (int i = t; i < 1152; i += 256) {
            const float e = expf(logits[i] - m);
            ebuf[i] = e;
            ls += e;
        }
#pragma unroll
        for (int off = 32; off; off >>= 1) ls += __shfl_xor(ls, off, 64);
        if ((t & 63) == 0) red[4 + (t >> 6)] = ls;
        __syncthreads();
        const float sumE = red[4] + red[5] + red[6] + red[7];
        float4 ps = make_float4(0.f, 0.f, 0.f, 0.f);
        if (iter == 1) {
            for (int i = ig; i < 1152; i += 64) {
                const float4 uh = uhat4(ub + i * 8, wo + (size_t)i * 128 + d4);
                ushort4 hb;
                __hip_bfloat16 q0 = __float2bfloat16(uh.x);
                __hip_bfloat16 q1 = __float2bfloat16(uh.y);
                __hip_bfloat16 q2 = __float2bfloat16(uh.z);
                __hip_bfloat16 q3 = __float2bfloat16(uh.w);
                hb.x = *(ushort*)&q0; hb.y = *(ushort*)&q1;
                hb.z = *(ushort*)&q2; hb.w = *(ushort*)&q3;
                *(ushort4*)(uh_s + i * 16 + d4) = hb;
                const float e = ebuf[i];
                ps.x += e * uh.x; ps.y += e * uh.y; ps.z += e * uh.z; ps.w += e * uh.w;
            }
        } else {
            for (int i = ig; i < 1152; i += 64) {
                const float4 uh = uh_from_lds(uh_s, i, d4);
                const float e = ebuf[i];
                ps.x += e * uh.x; ps.y += e * uh.y; ps.z += e * uh.z; ps.w += e * uh.w;
            }
        }
        psum[ig][d4 + 0] = ps.x; psum[ig][d4 + 1] = ps.y;
        psum[ig][d4 + 2] = ps.z; psum[ig][d4 + 3] = ps.w;
        __syncthreads();
        if (t < 16) {
            float s = 0.f;
            for (int g = 0; g < 64; ++g) s += psum[g][t];
            s /= sumE;
            float qn = s * s;
            qn += __shfl_xor(qn, 1, 16); qn += __shfl_xor(qn, 2, 16);
            qn += __shfl_xor(qn, 4, 16); qn += __shfl_xor(qn, 8, 16);
            v_s[t] = s * sqrtf(qn) / (1.f + qn);
        }
        __syncthreads();
        if (iter < 3) {
            const float v0 = v_s[d4 + 0], v1 = v_s[d4 + 1];
            const float v2 = v_s[d4 + 2], v3 = v_s[d4 + 3];
            for (int i = ig; i < 1152; i += 64) {
                const float4 uh = uh_from_lds(uh_s, i, d4);
                float pr = uh.x * v0 + uh.y * v1 + uh.z * v2 + uh.w * v3;
                pr += __shfl_xor(pr, 1, 64);
                pr += __shfl_xor(pr, 2, 64);
                if (dq == 0) logits[i] += pr;
            }
            __syncthreads();
        }
    }
    if (t < 16) out[((size_t)b * 10 + o) * 16 + t] = v_s[t];
}

// ===================== FALLBACK (R5 fp32 direct conv) ======================
#define WSL4 1344

__global__ __launch_bounds__(256) void wtrans_kernel(
    const float* __restrict__ w, float* __restrict__ wT)
{
    const int idx = blockIdx.x * 256 + threadIdx.x;
    if (idx >= 4 * 256 * 81 * 16) return;
    const int c      = idx & 15;
    const int k      = (idx >> 4) % 81;
    const int ic     = ((idx >> 4) / 81) % 256;
    const int octile = idx / (16 * 81 * 256);
    const int ocb    = octile * 64 + c * 4;
    float4 v;
    v.x = w[((size_t)(ocb + 0) * 256 + ic) * 81 + k];
    v.y = w[((size_t)(ocb + 1) * 256 + ic) * 81 + k];
    v.z = w[((size_t)(ocb + 2) * 256 + ic) * 81 + k];
    v.w = w[((size_t)(ocb + 3) * 256 + ic) * 81 + k];
    ((float4*)wT)[((size_t)octile * 256 + ic) * WSL4 + k * 16 + c] = v;
}

__global__ __launch_bounds__(384) void pcaps_kernel(
    const float* __restrict__ x, const float* __restrict__ wT,
    float* __restrict__ part)
{
    const int btile  = blockIdx.x;
    const int octile = blockIdx.y;
    const int ict    = blockIdx.z;
    const int t    = threadIdx.x;
    const int wave = t >> 6;
    const int lane = t & 63;
    __shared__ float4 w_s[2][WSL4];
    __shared__ float4 x_s[2][448];
    const int oc4  = (t & 15) * 4;
    const int slot = t >> 4;
    const int bb   = slot / 6;
    const int oy   = slot - 6 * bb;
    const int b0   = btile * 4;
    float acc[6][4];
#pragma unroll
    for (int p = 0; p < 6; ++p) {
        acc[p][0] = 0.f; acc[p][1] = 0.f; acc[p][2] = 0.f; acc[p][3] = 0.f;
    }
    const float*  xg   = x + (size_t)b0 * 102400 + (size_t)ict * 25600;
    const float4* wsrc = (const float4*)wT + ((size_t)octile * 256 + ict * 64) * WSL4;
#define PCAPS_STAGE(bf_, ic_)                                                  \
    {                                                                          \
        const float4* gsl = wsrc + (size_t)(ic_) * WSL4;                       \
        for (int ch = wave; ch < 21; ch += 6)                                  \
            gl_lds16(gsl + ch * 64 + lane, &w_s[bf_][ch * 64]);                \
        for (int ch = wave; ch < 7; ch += 6) {                                 \
            int idx = ch * 64 + lane;                                          \
            if (idx >= 400) idx = 0;                                           \
            const int xbb = idx / 100;                                         \
            const int off = idx - xbb * 100;                                   \
            const float* g = xg + (size_t)xbb * 102400 + (ic_) * 400 + off * 4;\
            gl_lds16(g, &x_s[bf_][ch * 64]);                                   \
        }                                                                      \
    }
    PCAPS_STAGE(0, 0);
    __syncthreads();
    int buf = 0;
    for (int ic = 0; ic < 64; ++ic) {
        if (ic < 63) PCAPS_STAGE(buf ^ 1, ic + 1);
        const float* xrow = (const float*)x_s[buf] + bb * 400;
        const float* wrow = (const float*)w_s[buf];
#pragma unroll
        for (int ky = 0; ky < 9; ++ky) {
            float rowv[20];
            const float4* xr = (const float4*)&xrow[(2 * oy + ky) * 20];
#pragma unroll
            for (int j = 0; j < 5; ++j) ((float4*)rowv)[j] = xr[j];
#pragma unroll
            for (int kx = 0; kx < 9; ++kx) {
                const float4 wv = *(const float4*)&wrow[(ky * 9 + kx) * 64 + oc4];
#pragma unroll
                for (int p = 0; p < 6; ++p) {
                    const float xv = rowv[2 * p + kx];
                    acc[p][0] += xv * wv.x; acc[p][1] += xv * wv.y;
                    acc[p][2] += xv * wv.z; acc[p][3] += xv * wv.w;
                }
            }
        }
        __syncthreads();
        buf ^= 1;
    }
#undef PCAPS_STAGE
    float* pb = part + ((size_t)ict * 128 + (b0 + bb)) * 9216;
    const int oc0 = octile * 64 + oc4;
    const int cap = oc0 >> 3;
    const int d0  = oc0 & 7;
#pragma unroll
    for (int p = 0; p < 6; ++p) {
        const int pos = oy * 6 + p;
        *(float4*)&pb[((size_t)cap * 36 + pos) * 8 + d0] =
            make_float4(acc[p][0], acc[p][1], acc[p][2], acc[p][3]);
    }
}

// ------------------------------- launcher ----------------------------------
extern "C" void kernel_launch(void* const* d_in, const int* in_sizes, int n_in,
                              void* d_out, int out_size, void* d_ws, size_t ws_size,
                              hipStream_t stream)
{
    const float* img = (const float*)d_in[0];
    const float* c1w = (const float*)d_in[1];
    const float* c1b = (const float*)d_in[2];
    const float* pw  = (const float*)d_in[3];
    const float* pb  = (const float*)d_in[4];
    const float* rw  = (const float*)d_in[5];
    float* out = (float*)d_out;
    char* ws = (char*)d_ws;

    if (ws_size >= 126091264ULL) {
        // fast path: fused-im2col split-bf16 MFMA GEMM (126.09 MB)
        float*  x    = (float*)(ws);                  // dead after xsplit
        float*  part = (float*)(ws);                  // aliases x
        float*  u    = (float*)(ws + 37748736);       // aliases x
        ushort* xTh  = (ushort*)(ws + 52428800);      // 26,214,400 B
        ushort* xTl  = (ushort*)(ws + 78643200);      // 26,214,400 B
        ushort* Wfh  = (ushort*)(ws + 104857600);     // 10,616,832 B
        ushort* Wfl  = (ushort*)(ws + 115474432);     // 10,616,832 B
        hipLaunchKernelGGL(conv1_kernel, dim3(4, 128), dim3(256), 0, stream, img, c1w, c1b, x);
        hipLaunchKernelGGL(xsplit_kernel, dim3(128, 8), dim3(256), 0, stream, x, xTh, xTl);
        hipLaunchKernelGGL(wsplit_kernel, dim3(256), dim3(256), 0, stream, pw, Wfh, Wfl);
        hipLaunchKernelGGL(gemm5_kernel, dim3(576), dim3(512), 0, stream, xTh, xTl, Wfh, Wfl, part);
        hipLaunchKernelGGL(squash_kernel, dim3(576), dim3(256), 0, stream, part, pb, u, 8);
        hipLaunchKernelGGL(routing_kernel, dim3(128, 10), dim3(256), 0, stream, u, rw, out);
    } else {
        // fallback: R5 fp32 direct conv (97.9 MB, proven)
        float* x    = (float*)(ws);
        float* part = (float*)(ws + 52428800);
        float* u    = (float*)(ws + 52428800 + 18874368);
        float* wT   = (float*)(ws + 52428800 + 18874368 + 4718592);
        hipLaunchKernelGGL(wtrans_kernel, dim3((4 * 256 * 81 * 16 + 255) / 256), dim3(256), 0, stream, pw, wT);
        hipLaunchKernelGGL(conv1_kernel, dim3(4, 128), dim3(256), 0, stream, img, c1w, c1b, x);
        hipLaunchKernelGGL(pcaps_kernel, dim3(32, 4, 4), dim3(384), 0, stream, x, wT, part);
        hipLaunchKernelGGL(squash_kernel, dim3(576), dim3(256), 0, stream, part, pb, u, 4);
        hipLaunchKernelGGL(routing_kernel, dim3(128, 10), dim3(256), 0, stream, u, rw, out);
    }
}